// Round 2
// baseline (40288.724 us; speedup 1.0000x reference)
//
#include <hip/hip_runtime.h>
#include <math.h>

#define BB 64
#define TT 256
#define VV 2000
#define EE 256
#define HD 256
#define ENC 256
#define AA 256
#define PP 512   // HI*WI = 16*32
#define NBLK 256

// ---------------- precompute kernels ----------------

__global__ void k_mean(const float* __restrict__ enc, float* __restrict__ meanb) {
    int b = blockIdx.x, c = threadIdx.x;
    const float4* p4 = reinterpret_cast<const float4*>(enc + ((size_t)b*ENC + c)*PP);
    float s = 0.f;
    for (int i = 0; i < PP/4; ++i) { float4 v = p4[i]; s += v.x + v.y + v.z + v.w; }
    meanb[b*ENC + c] = s * (1.0f/PP);
}

__global__ void k_init(const float* __restrict__ meanb,
                       const float* __restrict__ Winith, const float* __restrict__ binith,
                       const float* __restrict__ Winitc, const float* __restrict__ binitc,
                       float* __restrict__ h0, float* __restrict__ c0,
                       float* __restrict__ h1i, float* __restrict__ c1) {
    __shared__ float ms[ENC];
    int b = blockIdx.x, j = threadIdx.x;
    ms[j] = meanb[b*ENC + j];
    __syncthreads();
    float ah = binith[j], ac = binitc[j];
    const float4* wh = (const float4*)(Winith + (size_t)j*ENC);
    const float4* wc = (const float4*)(Winitc + (size_t)j*ENC);
    const float4* m4 = (const float4*)ms;
    for (int k = 0; k < ENC/4; ++k) {
        float4 m = m4[k], a = wh[k], b2 = wc[k];
        ah += a.x*m.x + a.y*m.y + a.z*m.z + a.w*m.w;
        ac += b2.x*m.x + b2.y*m.y + b2.z*m.z + b2.w*m.w;
    }
    float hv = tanhf(ah), cv = tanhf(ac);
    h0[b*HD + j] = hv; c0[b*HD + j] = cv;
    h1i[b*HD + j] = hv; c1[b*HD + j] = cv;
}

__global__ void k_att1T(const float* __restrict__ enc, const float* __restrict__ Wae,
                        const float* __restrict__ bae, float* __restrict__ att1T) {
    __shared__ float wsm[16][ENC];
    int a0 = blockIdx.x * 16, b = blockIdx.y, p = threadIdx.x;
    for (int i = threadIdx.x; i < 16*ENC; i += 512) wsm[i >> 8][i & 255] = Wae[(size_t)a0*ENC + i];
    __syncthreads();
    float acc[16];
    #pragma unroll
    for (int i = 0; i < 16; ++i) acc[i] = 0.f;
    const float* eb = enc + (size_t)b*ENC*PP + p;
    for (int c = 0; c < ENC; ++c) {
        float v = eb[(size_t)c*PP];
        #pragma unroll
        for (int i = 0; i < 16; ++i) acc[i] += v * wsm[i][c];
    }
    for (int i = 0; i < 16; ++i)
        att1T[((size_t)b*AA + a0 + i)*PP + p] = acc[i] + bae[a0 + i];
}

// ---------------- persistent main loop ----------------

struct KP {
    const float* enc; const int* caps; const float* emb;
    const float* Wad; const float* bad; const float* Wfa; const float* bfa;
    const float* Wih0; const float* Whh0; const float* bih0; const float* bhh0;
    const float* Wih1; const float* Whh1; const float* bih1; const float* bhh1;
    const float* att1T; const float* h1init;
    float* H1all; float* h0b; float* c0; float* c1;
    float* att2g; float* ctxU; float* Zp; float* wsout;
    unsigned* bar;   // [0]=cnt, [1]=gen
};

// shared-memory phase union (26,048 B)
union SU {
    struct { float wads[8][260]; float h1s[8][260]; float red[4][64]; } A;
    struct { float a2[AA]; float wf[AA]; float ps[2][128]; float es[128]; } B;
    struct { float xt[8][776]; float gsm[8][4][9]; float zr[8]; int cps[8]; } C;
    struct { float xt[8][520]; float gsm[8][4][9]; } D;
};

__device__ __forceinline__ void grid_bar(unsigned* cnt, unsigned* gen, unsigned& lg) {
    __syncthreads();
    if (threadIdx.x == 0) {
        __threadfence();
        unsigned old = __hip_atomic_fetch_add(cnt, 1u, __ATOMIC_ACQ_REL, __HIP_MEMORY_SCOPE_AGENT);
        if (old == NBLK - 1) {
            __hip_atomic_store(cnt, 0u, __ATOMIC_RELAXED, __HIP_MEMORY_SCOPE_AGENT);
            __hip_atomic_store(gen, lg + 1, __ATOMIC_RELEASE, __HIP_MEMORY_SCOPE_AGENT);
        } else {
            while (__hip_atomic_load(gen, __ATOMIC_ACQUIRE, __HIP_MEMORY_SCOPE_AGENT) == lg) {}
        }
        __threadfence();
    }
    lg++;
    __syncthreads();
}

__global__ __launch_bounds__(256, 1) void main_loop(KP P) {
    __shared__ float att1s[256*128];   // 128 KB: this block's [a][p_l] slice
    __shared__ SU u;

    const int bid = blockIdx.x, tid = threadIdx.x;
    const int b_sc = bid >> 2, ch = bid & 3, p0 = ch * 128;   // score mapping
    const int a0 = (bid & 31) * 8, bA0 = (bid >> 5) * 8;      // att2 mapping
    const int j0 = (bid & 31) * 8, bL0 = (bid >> 5) * 8;      // lstm mapping

    // one-time: load att1 slice into LDS (stays for all 256 steps)
    for (int i = tid; i < 256*128; i += 256) {
        int a = i >> 7, pl = i & 127;
        att1s[i] = P.att1T[((size_t)b_sc*AA + a)*PP + p0 + pl];
    }

    unsigned lg = 0;
    unsigned* cnt = P.bar;
    unsigned* gen = P.bar + 1;

    for (int t = 0; t < TT; ++t) {
        const float* h1p = (t == 0) ? P.h1init : (P.H1all + (size_t)(t-1)*BB*HD);
        int rp = t & 1, wp = rp ^ 1;
        const float* h0p = P.h0b + (size_t)rp*BB*HD;
        float*       h0n = P.h0b + (size_t)wp*BB*HD;
        float*       h1o = P.H1all + (size_t)t*BB*HD;

        // ---- phase A: att2[b][a] = h1p[b]@Wad[a]^T + bad[a] ----
        {
            const float4* wsrc = (const float4*)(P.Wad + (size_t)a0*HD);
            const float4* hsrc = (const float4*)(h1p + (size_t)bA0*HD);
            for (int i = tid; i < 512; i += 256) {
                int r = i >> 6, c4 = i & 63;
                *(float4*)&u.A.wads[r][c4*4] = wsrc[i];
                *(float4*)&u.A.h1s[r][c4*4]  = hsrc[i];
            }
            __syncthreads();
            int kq = tid >> 6, pr = tid & 63, a_l = pr & 7, b_l = pr >> 3;
            const float4* wr = (const float4*)&u.A.wads[a_l][kq*64];
            const float4* hr = (const float4*)&u.A.h1s[b_l][kq*64];
            float acc = 0.f;
            #pragma unroll
            for (int k = 0; k < 16; ++k) {
                float4 w = wr[k], h = hr[k];
                acc += w.x*h.x + w.y*h.y + w.z*h.z + w.w*h.w;
            }
            u.A.red[kq][pr] = acc;
            __syncthreads();
            if (tid < 64) {
                float s = u.A.red[0][tid] + u.A.red[1][tid] + u.A.red[2][tid] + u.A.red[3][tid];
                int a = a0 + (tid & 7), bb = bA0 + (tid >> 3);
                P.att2g[bb*AA + a] = s + P.bad[a];
            }
        }
        grid_bar(cnt, gen, lg);

        // ---- phase B: score + softmax(unnormalized) + partial ctx ----
        {
            u.B.a2[tid] = P.att2g[b_sc*AA + tid];
            u.B.wf[tid] = P.Wfa[tid];
            __syncthreads();
            {
                int p_l = tid & 127, half = tid >> 7;
                const float* ap = att1s + (half*128)*128 + p_l;
                float s = half ? 0.f : P.bfa[0];
                #pragma unroll 4
                for (int a = 0; a < 128; ++a) {
                    float x = ap[a*128] + u.B.a2[half*128 + a];
                    float e2 = __expf(2.f * x);          // tanh(x) = 1 - 2/(e^2x+1)
                    s += u.B.wf[half*128 + a] * (1.f - 2.f/(e2 + 1.f));
                }
                u.B.ps[half][p_l] = s;
            }
            __syncthreads();
            if (tid < 128) {
                float e = __expf(u.B.ps[0][tid] + u.B.ps[1][tid]);
                u.B.es[tid] = e;
                P.wsout[((size_t)b_sc*TT + t)*PP + p0 + tid] = e;
            }
            __syncthreads();
            if (tid < 64) {
                float z = u.B.es[tid] + u.B.es[tid + 64];
                for (int o = 32; o > 0; o >>= 1) z += __shfl_down(z, o, 64);
                if (tid == 0) P.Zp[b_sc*4 + ch] = z;
            }
            float acc = 0.f;
            const float4* ep = (const float4*)(P.enc + ((size_t)b_sc*ENC + tid)*PP + p0);
            for (int k = 0; k < 32; ++k) {
                float4 v = ep[k];
                acc += u.B.es[k*4]*v.x + u.B.es[k*4+1]*v.y + u.B.es[k*4+2]*v.z + u.B.es[k*4+3]*v.w;
            }
            P.ctxU[(b_sc*4 + ch)*ENC + tid] = acc;
        }
        grid_bar(cnt, gen, lg);

        // ---- phase C: LSTM layer 0 (c0 updated in place) ----
        {
            if (tid < 8) {
                int b = bL0 + tid;
                u.C.zr[tid] = 1.f / (P.Zp[b*4] + P.Zp[b*4+1] + P.Zp[b*4+2] + P.Zp[b*4+3]);
                u.C.cps[tid] = P.caps[b*TT + t];
            }
            __syncthreads();
            for (int i = tid; i < 8*768; i += 256) {
                int bl = i / 768, k = i - bl*768; int b = bL0 + bl;
                float v;
                if (k < 256)      v = P.emb[(size_t)u.C.cps[bl]*EE + k];
                else if (k < 512) { int c = k - 256;
                    v = (P.ctxU[(b*4)*ENC + c] + P.ctxU[(b*4+1)*ENC + c] +
                         P.ctxU[(b*4+2)*ENC + c] + P.ctxU[(b*4+3)*ENC + c]) * u.C.zr[bl]; }
                else              v = h0p[b*HD + k - 512];
                u.C.xt[bl][k] = v;
            }
            __syncthreads();
            int b_l = tid & 7, gate = (tid >> 3) & 3, j_l = tid >> 5;
            int g = gate*HD + j0 + j_l;
            float accA = P.bih0[g] + P.bhh0[g], accB = 0.f;
            const float4* wi = (const float4*)(P.Wih0 + (size_t)g*512);
            const float4* xb = (const float4*)u.C.xt[b_l];
            #pragma unroll 4
            for (int k = 0; k < 128; k += 2) {
                float4 w0 = wi[k],   x0 = xb[k];
                float4 w1 = wi[k+1], x1 = xb[k+1];
                accA += w0.x*x0.x + w0.y*x0.y + w0.z*x0.z + w0.w*x0.w;
                accB += w1.x*x1.x + w1.y*x1.y + w1.z*x1.z + w1.w*x1.w;
            }
            const float4* wh = (const float4*)(P.Whh0 + (size_t)g*HD);
            const float4* xh = (const float4*)(u.C.xt[b_l] + 512);
            #pragma unroll 4
            for (int k = 0; k < 64; k += 2) {
                float4 w0 = wh[k],   x0 = xh[k];
                float4 w1 = wh[k+1], x1 = xh[k+1];
                accA += w0.x*x0.x + w0.y*x0.y + w0.z*x0.z + w0.w*x0.w;
                accB += w1.x*x1.x + w1.y*x1.y + w1.z*x1.z + w1.w*x1.w;
            }
            u.C.gsm[j_l][gate][b_l] = accA + accB;
            __syncthreads();
            if (tid < 64) {
                int jl = tid >> 3, bl = tid & 7; int b = bL0 + bl, j = j0 + jl;
                float gi = u.C.gsm[jl][0][bl], gf = u.C.gsm[jl][1][bl];
                float gg = u.C.gsm[jl][2][bl], go = u.C.gsm[jl][3][bl];
                float si = 1.f/(1.f + __expf(-gi)), sf = 1.f/(1.f + __expf(-gf)), so = 1.f/(1.f + __expf(-go));
                float c2 = sf * P.c0[b*HD + j] + si * tanhf(gg);
                P.c0[b*HD + j] = c2;
                h0n[b*HD + j] = so * tanhf(c2);
            }
        }
        grid_bar(cnt, gen, lg);

        // ---- phase D: LSTM layer 1 (c1 in place), writes H1all[t] ----
        {
            for (int i = tid; i < 8*512; i += 256) {
                int bl = i >> 9, k = i & 511; int b = bL0 + bl;
                u.D.xt[bl][k] = (k < 256) ? h0n[b*HD + k] : h1p[b*HD + k - 256];
            }
            __syncthreads();
            int b_l = tid & 7, gate = (tid >> 3) & 3, j_l = tid >> 5;
            int g = gate*HD + j0 + j_l;
            float accA = P.bih1[g] + P.bhh1[g], accB = 0.f;
            const float4* wi = (const float4*)(P.Wih1 + (size_t)g*HD);
            const float4* xb = (const float4*)u.D.xt[b_l];
            #pragma unroll 4
            for (int k = 0; k < 64; k += 2) {
                float4 w0 = wi[k],   x0 = xb[k];
                float4 w1 = wi[k+1], x1 = xb[k+1];
                accA += w0.x*x0.x + w0.y*x0.y + w0.z*x0.z + w0.w*x0.w;
                accB += w1.x*x1.x + w1.y*x1.y + w1.z*x1.z + w1.w*x1.w;
            }
            const float4* wh = (const float4*)(P.Whh1 + (size_t)g*HD);
            const float4* xh = (const float4*)(u.D.xt[b_l] + 256);
            #pragma unroll 4
            for (int k = 0; k < 64; k += 2) {
                float4 w0 = wh[k],   x0 = xh[k];
                float4 w1 = wh[k+1], x1 = xh[k+1];
                accA += w0.x*x0.x + w0.y*x0.y + w0.z*x0.z + w0.w*x0.w;
                accB += w1.x*x1.x + w1.y*x1.y + w1.z*x1.z + w1.w*x1.w;
            }
            u.D.gsm[j_l][gate][b_l] = accA + accB;
            __syncthreads();
            if (tid < 64) {
                int jl = tid >> 3, bl = tid & 7; int b = bL0 + bl, j = j0 + jl;
                float gi = u.D.gsm[jl][0][bl], gf = u.D.gsm[jl][1][bl];
                float gg = u.D.gsm[jl][2][bl], go = u.D.gsm[jl][3][bl];
                float si = 1.f/(1.f + __expf(-gi)), sf = 1.f/(1.f + __expf(-gf)), so = 1.f/(1.f + __expf(-go));
                float c2 = sf * P.c1[b*HD + j] + si * tanhf(gg);
                P.c1[b*HD + j] = c2;
                h1o[b*HD + j] = so * tanhf(c2);
            }
        }
        grid_bar(cnt, gen, lg);
    }
}

// ---------------- finalization ----------------

__global__ void f1_norm(float* __restrict__ wsout) {
    int t = blockIdx.x, b = blockIdx.y, tid = threadIdx.x;
    float4* row = (float4*)(wsout + ((size_t)b*TT + t)*PP);
    float4 v = row[tid];
    float s = v.x + v.y + v.z + v.w;
    __shared__ float zz[2];
    for (int o = 32; o > 0; o >>= 1) s += __shfl_down(s, o, 64);
    if ((tid & 63) == 0) zz[tid >> 6] = s;
    __syncthreads();
    float r = 1.f / (zz[0] + zz[1]);
    v.x *= r; v.y *= r; v.z *= r; v.w *= r;
    row[tid] = v;
}

__global__ __launch_bounds__(256)
void f2_out(const float* __restrict__ H1all, const float* __restrict__ Wout,
            const float* __restrict__ bout, float* __restrict__ out0) {
    __shared__ float Hs[16][260];
    int vt = blockIdx.x, rt = blockIdx.y, tid = threadIdx.x;
    int r0 = rt * 16;
    for (int i = tid; i < 16*256; i += 256) {
        int rl = i >> 8, c = i & 255;
        Hs[rl][c] = H1all[(size_t)(r0 + rl)*HD + c];
    }
    __syncthreads();
    int r_l = tid & 15, v_l = tid >> 4;
    int r = r0 + r_l; int tt = r >> 6, bb2 = r & 63;
    float* orow = out0 + ((size_t)bb2*TT + tt)*VV;
    const float4* hs = (const float4*)Hs[r_l];
    int vbase = vt*128 + v_l*8;
    for (int i = 0; i < 8; ++i) {
        int v = vbase + i;
        if (v >= VV) break;
        const float4* wr = (const float4*)(Wout + (size_t)v*HD);
        float accA = 0.f, accB = 0.f;
        #pragma unroll 4
        for (int k = 0; k < 64; k += 2) {
            float4 w0 = wr[k],   h0 = hs[k];
            float4 w1 = wr[k+1], h1 = hs[k+1];
            accA += w0.x*h0.x + w0.y*h0.y + w0.z*h0.z + w0.w*h0.w;
            accB += w1.x*h1.x + w1.y*h1.y + w1.z*h1.z + w1.w*h1.w;
        }
        orow[v] = accA + accB + bout[v];
    }
}

// ---------------- host ----------------

extern "C" void kernel_launch(void* const* d_in, const int* in_sizes, int n_in,
                              void* d_out, int out_size, void* d_ws, size_t ws_size,
                              hipStream_t stream) {
    const float* enc    = (const float*)d_in[0];
    const int*   caps   = (const int*)  d_in[1];
    const float* emb    = (const float*)d_in[2];
    const float* Wae    = (const float*)d_in[3];
    const float* bae    = (const float*)d_in[4];
    const float* Wad    = (const float*)d_in[5];
    const float* bad    = (const float*)d_in[6];
    const float* Wfa    = (const float*)d_in[7];
    const float* bfa    = (const float*)d_in[8];
    const float* Winith = (const float*)d_in[9];
    const float* binith = (const float*)d_in[10];
    const float* Winitc = (const float*)d_in[11];
    const float* binitc = (const float*)d_in[12];
    const float* Wih0   = (const float*)d_in[13];
    const float* Whh0   = (const float*)d_in[14];
    const float* bih0   = (const float*)d_in[15];
    const float* bhh0   = (const float*)d_in[16];
    const float* Wih1   = (const float*)d_in[17];
    const float* Whh1   = (const float*)d_in[18];
    const float* bih1   = (const float*)d_in[19];
    const float* bhh1   = (const float*)d_in[20];
    const float* Wout   = (const float*)d_in[21];
    const float* bout   = (const float*)d_in[22];

    // workspace layout (floats); total 12,763,394 floats ≈ 51.05 MB
    float* ws     = (float*)d_ws;
    float* att1T  = ws;                      // 8,388,608
    float* H1all  = ws + 8388608;            // 4,194,304
    float* meanb  = ws + 12582912;           //    16,384
    float* h0b    = ws + 12599296;           //    32,768 (double buffer)
    float* c0     = ws + 12632064;           //    16,384 (in-place)
    float* c1     = ws + 12648448;           //    16,384 (in-place)
    float* h1init = ws + 12664832;           //    16,384
    float* att2g  = ws + 12681216;           //    16,384
    float* ctxU   = ws + 12697600;           //    65,536
    float* Zp     = ws + 12763136;           //       256
    unsigned* bar = (unsigned*)(ws + 12763392); // 2 uints

    float* out0  = (float*)d_out;
    float* wsout = out0 + (size_t)BB*TT*VV;

    hipMemsetAsync((void*)bar, 0, 2*sizeof(unsigned), stream);
    hipLaunchKernelGGL(k_mean,  dim3(BB),     dim3(256), 0, stream, enc, meanb);
    hipLaunchKernelGGL(k_init,  dim3(BB),     dim3(256), 0, stream, meanb, Winith, binith,
                       Winitc, binitc, h0b, c0, h1init, c1);
    hipLaunchKernelGGL(k_att1T, dim3(16, BB), dim3(512), 0, stream, enc, Wae, bae, att1T);

    KP kp;
    kp.enc = enc; kp.caps = caps; kp.emb = emb;
    kp.Wad = Wad; kp.bad = bad; kp.Wfa = Wfa; kp.bfa = bfa;
    kp.Wih0 = Wih0; kp.Whh0 = Whh0; kp.bih0 = bih0; kp.bhh0 = bhh0;
    kp.Wih1 = Wih1; kp.Whh1 = Whh1; kp.bih1 = bih1; kp.bhh1 = bhh1;
    kp.att1T = att1T; kp.h1init = h1init;
    kp.H1all = H1all; kp.h0b = h0b; kp.c0 = c0; kp.c1 = c1;
    kp.att2g = att2g; kp.ctxU = ctxU; kp.Zp = Zp; kp.wsout = wsout;
    kp.bar = bar;

    void* args[] = { &kp };
    hipLaunchCooperativeKernel((const void*)main_loop, dim3(NBLK), dim3(256), args, 0, stream);

    hipLaunchKernelGGL(f1_norm, dim3(TT, BB),  dim3(128), 0, stream, wsout);
    hipLaunchKernelGGL(f2_out,  dim3(16, 1024), dim3(256), 0, stream, H1all, Wout, bout, out0);
}

// Round 3
// 38250.735 us; speedup vs baseline: 1.0533x; 1.0533x over previous
//
#include <hip/hip_runtime.h>
#include <math.h>

#define BB 64
#define TT 256
#define VV 2000
#define EE 256
#define HD 256
#define ENC 256
#define AA 256
#define PP 512   // HI*WI = 16*32
#define NBLK 256

// ---------------- precompute kernels ----------------

__global__ void k_mean(const float* __restrict__ enc, float* __restrict__ meanb) {
    int b = blockIdx.x, c = threadIdx.x;
    const float4* p4 = reinterpret_cast<const float4*>(enc + ((size_t)b*ENC + c)*PP);
    float s = 0.f;
    for (int i = 0; i < PP/4; ++i) { float4 v = p4[i]; s += v.x + v.y + v.z + v.w; }
    meanb[b*ENC + c] = s * (1.0f/PP);
}

__global__ void k_init(const float* __restrict__ meanb,
                       const float* __restrict__ Winith, const float* __restrict__ binith,
                       const float* __restrict__ Winitc, const float* __restrict__ binitc,
                       float* __restrict__ h0, float* __restrict__ c0,
                       float* __restrict__ h1i, float* __restrict__ c1) {
    __shared__ float ms[ENC];
    int b = blockIdx.x, j = threadIdx.x;
    ms[j] = meanb[b*ENC + j];
    __syncthreads();
    float ah = binith[j], ac = binitc[j];
    const float4* wh = (const float4*)(Winith + (size_t)j*ENC);
    const float4* wc = (const float4*)(Winitc + (size_t)j*ENC);
    const float4* m4 = (const float4*)ms;
    for (int k = 0; k < ENC/4; ++k) {
        float4 m = m4[k], a = wh[k], b2 = wc[k];
        ah += a.x*m.x + a.y*m.y + a.z*m.z + a.w*m.w;
        ac += b2.x*m.x + b2.y*m.y + b2.z*m.z + b2.w*m.w;
    }
    float hv = tanhf(ah), cv = tanhf(ac);
    h0[b*HD + j] = hv; c0[b*HD + j] = cv;
    h1i[b*HD + j] = hv; c1[b*HD + j] = cv;
}

__global__ void k_att1T(const float* __restrict__ enc, const float* __restrict__ Wae,
                        const float* __restrict__ bae, float* __restrict__ att1T) {
    __shared__ float wsm[16][ENC];
    int a0 = blockIdx.x * 16, b = blockIdx.y, p = threadIdx.x;
    for (int i = threadIdx.x; i < 16*ENC; i += 512) wsm[i >> 8][i & 255] = Wae[(size_t)a0*ENC + i];
    __syncthreads();
    float acc[16];
    #pragma unroll
    for (int i = 0; i < 16; ++i) acc[i] = 0.f;
    const float* eb = enc + (size_t)b*ENC*PP + p;
    for (int c = 0; c < ENC; ++c) {
        float v = eb[(size_t)c*PP];
        #pragma unroll
        for (int i = 0; i < 16; ++i) acc[i] += v * wsm[i][c];
    }
    for (int i = 0; i < 16; ++i)
        att1T[((size_t)b*AA + a0 + i)*PP + p] = acc[i] + bae[a0 + i];
}

__device__ __forceinline__ unsigned short f2bf(float f) {
    unsigned u = __float_as_uint(f);
    return (unsigned short)((u + 0x7fffu + ((u >> 16) & 1u)) >> 16);
}

// bf16 copy of enc (RNE) for the per-step ctx dot: 64 KB/block/step, L2-resident
__global__ void k_encbf(const float* __restrict__ enc, unsigned short* __restrict__ encbf) {
    size_t i0 = ((size_t)blockIdx.x*256 + threadIdx.x)*8;
    const float4* s = (const float4*)(enc + i0);
    float4 a = s[0], b = s[1];
    ushort4 lo = { f2bf(a.x), f2bf(a.y), f2bf(a.z), f2bf(a.w) };
    ushort4 hi = { f2bf(b.x), f2bf(b.y), f2bf(b.z), f2bf(b.w) };
    *(ushort4*)(encbf + i0)     = lo;
    *(ushort4*)(encbf + i0 + 4) = hi;
}

// ---------------- persistent main loop ----------------

struct KP {
    const float* enc; const int* caps; const float* emb;
    const float* Wad; const float* bad; const float* Wfa; const float* bfa;
    const float* Wih0; const float* Whh0; const float* bih0; const float* bhh0;
    const float* Wih1; const float* Whh1; const float* bih1; const float* bhh1;
    const float* att1T; const float* h1init; const unsigned short* encbf;
    float* H1all; float* h0b; float* c0; float* c1;
    float* att2g; float* ctxU; float* Zp; float* wsout;
    unsigned* bar;   // [g*16]=group cnt (g<8), [128]=root cnt, [144]=gen
};

// shared-memory phase union (26,048 B)
union SU {
    struct { float wads[8][260]; float h1s[8][260]; float red[4][64]; } A;
    struct { float a2[AA]; float wf[AA]; float ps[2][128]; float es[128]; } B;
    struct { float xt[8][776]; float gsm[8][4][9]; float zr[8]; int cps[8]; } C;
    struct { float xt[8][520]; float gsm[8][4][9]; } D;
};

// hierarchical grid barrier: monotonic counters, chained signal, s_sleep backoff
__device__ __forceinline__ void grid_bar(unsigned* barb, unsigned k, int bid) {
    __syncthreads();
    if (threadIdx.x == 0) {
        __threadfence();
        unsigned old = __hip_atomic_fetch_add(barb + ((bid >> 5) * 16), 1u,
                                              __ATOMIC_ACQ_REL, __HIP_MEMORY_SCOPE_AGENT);
        if (old == 32u*k - 1u) {                       // last arriver of this group
            unsigned ro = __hip_atomic_fetch_add(barb + 128, 1u,
                                                 __ATOMIC_ACQ_REL, __HIP_MEMORY_SCOPE_AGENT);
            if (ro == 8u*k - 1u) {                     // last group overall
                __hip_atomic_store(barb + 144, k, __ATOMIC_RELEASE, __HIP_MEMORY_SCOPE_AGENT);
            }
        }
        while (__hip_atomic_load(barb + 144, __ATOMIC_ACQUIRE, __HIP_MEMORY_SCOPE_AGENT) < k)
            __builtin_amdgcn_s_sleep(2);
        __threadfence();
    }
    __syncthreads();
}

__global__ __launch_bounds__(256, 1) void main_loop(KP P) {
    __shared__ float att1s[256*128];   // 128 KB: this block's [a][p_l] slice, fp32
    __shared__ SU u;

    const int bid = blockIdx.x, tid = threadIdx.x;
    const int b_sc = bid >> 2, ch = bid & 3, p0 = ch * 128;   // score mapping
    const int a0 = (bid & 31) * 8, bA0 = (bid >> 5) * 8;      // att2 mapping
    const int j0 = (bid & 31) * 8, bL0 = (bid >> 5) * 8;      // lstm mapping

    // one-time: load att1 slice into LDS (stays for all 256 steps)
    for (int i = tid; i < 256*128; i += 256) {
        int a = i >> 7, pl = i & 127;
        att1s[i] = P.att1T[((size_t)b_sc*AA + a)*PP + p0 + pl];
    }

    unsigned bk = 0;

    for (int t = 0; t < TT; ++t) {
        const float* h1p = (t == 0) ? P.h1init : (P.H1all + (size_t)(t-1)*BB*HD);
        int rp = t & 1, wp = rp ^ 1;
        const float* h0p = P.h0b + (size_t)rp*BB*HD;
        float*       h0n = P.h0b + (size_t)wp*BB*HD;
        float*       h1o = P.H1all + (size_t)t*BB*HD;

        // ---- phase A: att2[b][a] = h1p[b]@Wad[a]^T + bad[a] ----
        {
            const float4* wsrc = (const float4*)(P.Wad + (size_t)a0*HD);
            const float4* hsrc = (const float4*)(h1p + (size_t)bA0*HD);
            for (int i = tid; i < 512; i += 256) {
                int r = i >> 6, c4 = i & 63;
                *(float4*)&u.A.wads[r][c4*4] = wsrc[i];
                *(float4*)&u.A.h1s[r][c4*4]  = hsrc[i];
            }
            __syncthreads();
            int kq = tid >> 6, pr = tid & 63, a_l = pr & 7, b_l = pr >> 3;
            const float4* wr = (const float4*)&u.A.wads[a_l][kq*64];
            const float4* hr = (const float4*)&u.A.h1s[b_l][kq*64];
            float acc = 0.f;
            #pragma unroll
            for (int k = 0; k < 16; ++k) {
                float4 w = wr[k], h = hr[k];
                acc += w.x*h.x + w.y*h.y + w.z*h.z + w.w*h.w;
            }
            u.A.red[kq][pr] = acc;
            __syncthreads();
            if (tid < 64) {
                float s = u.A.red[0][tid] + u.A.red[1][tid] + u.A.red[2][tid] + u.A.red[3][tid];
                int a = a0 + (tid & 7), bb = bA0 + (tid >> 3);
                P.att2g[bb*AA + a] = s + P.bad[a];
            }
        }
        grid_bar(P.bar, ++bk, bid);

        // ---- phase B: score + softmax(unnormalized) + partial ctx ----
        {
            u.B.a2[tid] = P.att2g[b_sc*AA + tid];
            u.B.wf[tid] = P.Wfa[tid];
            __syncthreads();
            {
                int p_l = tid & 127, half = tid >> 7;
                const float* ap = att1s + (half*128)*128 + p_l;
                float s = half ? 0.f : P.bfa[0];
                #pragma unroll 4
                for (int a = 0; a < 128; ++a) {
                    float x = ap[a*128] + u.B.a2[half*128 + a];
                    float e2 = __expf(2.f * x);          // tanh(x) = 1 - 2/(e^2x+1)
                    s += u.B.wf[half*128 + a] * (1.f - 2.f/(e2 + 1.f));
                }
                u.B.ps[half][p_l] = s;
            }
            __syncthreads();
            if (tid < 128) {
                float e = __expf(u.B.ps[0][tid] + u.B.ps[1][tid]);
                u.B.es[tid] = e;
                P.wsout[((size_t)b_sc*TT + t)*PP + p0 + tid] = e;
            }
            __syncthreads();
            if (tid < 64) {
                float z = u.B.es[tid] + u.B.es[tid + 64];
                for (int o = 32; o > 0; o >>= 1) z += __shfl_down(z, o, 64);
                if (tid == 0) P.Zp[b_sc*4 + ch] = z;
            }
            // partial ctx from bf16 enc copy (L2-resident, fixed block mapping)
            float acc = 0.f;
            const uint4* ep = (const uint4*)(P.encbf + ((size_t)b_sc*ENC + tid)*PP + p0);
            #pragma unroll 4
            for (int k = 0; k < 16; ++k) {
                uint4 v = ep[k];
                const float* e8 = &u.B.es[k*8];
                acc += e8[0]*__uint_as_float(v.x << 16) + e8[1]*__uint_as_float(v.x & 0xffff0000u)
                     + e8[2]*__uint_as_float(v.y << 16) + e8[3]*__uint_as_float(v.y & 0xffff0000u)
                     + e8[4]*__uint_as_float(v.z << 16) + e8[5]*__uint_as_float(v.z & 0xffff0000u)
                     + e8[6]*__uint_as_float(v.w << 16) + e8[7]*__uint_as_float(v.w & 0xffff0000u);
            }
            P.ctxU[(b_sc*4 + ch)*ENC + tid] = acc;
        }
        grid_bar(P.bar, ++bk, bid);

        // ---- phase C: LSTM layer 0 (c0 updated in place) ----
        {
            if (tid < 8) {
                int b = bL0 + tid;
                u.C.zr[tid] = 1.f / (P.Zp[b*4] + P.Zp[b*4+1] + P.Zp[b*4+2] + P.Zp[b*4+3]);
                u.C.cps[tid] = P.caps[b*TT + t];
            }
            __syncthreads();
            for (int i = tid; i < 8*768; i += 256) {
                int bl = i / 768, k = i - bl*768; int b = bL0 + bl;
                float v;
                if (k < 256)      v = P.emb[(size_t)u.C.cps[bl]*EE + k];
                else if (k < 512) { int c = k - 256;
                    v = (P.ctxU[(b*4)*ENC + c] + P.ctxU[(b*4+1)*ENC + c] +
                         P.ctxU[(b*4+2)*ENC + c] + P.ctxU[(b*4+3)*ENC + c]) * u.C.zr[bl]; }
                else              v = h0p[b*HD + k - 512];
                u.C.xt[bl][k] = v;
            }
            __syncthreads();
            int b_l = tid & 7, gate = (tid >> 3) & 3, j_l = tid >> 5;
            int g = gate*HD + j0 + j_l;
            float accA = P.bih0[g] + P.bhh0[g], accB = 0.f;
            const float4* wi = (const float4*)(P.Wih0 + (size_t)g*512);
            const float4* xb = (const float4*)u.C.xt[b_l];
            #pragma unroll 4
            for (int k = 0; k < 128; k += 2) {
                float4 w0 = wi[k],   x0 = xb[k];
                float4 w1 = wi[k+1], x1 = xb[k+1];
                accA += w0.x*x0.x + w0.y*x0.y + w0.z*x0.z + w0.w*x0.w;
                accB += w1.x*x1.x + w1.y*x1.y + w1.z*x1.z + w1.w*x1.w;
            }
            const float4* wh = (const float4*)(P.Whh0 + (size_t)g*HD);
            const float4* xh = (const float4*)(u.C.xt[b_l] + 512);
            #pragma unroll 4
            for (int k = 0; k < 64; k += 2) {
                float4 w0 = wh[k],   x0 = xh[k];
                float4 w1 = wh[k+1], x1 = xh[k+1];
                accA += w0.x*x0.x + w0.y*x0.y + w0.z*x0.z + w0.w*x0.w;
                accB += w1.x*x1.x + w1.y*x1.y + w1.z*x1.z + w1.w*x1.w;
            }
            u.C.gsm[j_l][gate][b_l] = accA + accB;
            __syncthreads();
            if (tid < 64) {
                int jl = tid >> 3, bl = tid & 7; int b = bL0 + bl, j = j0 + jl;
                float gi = u.C.gsm[jl][0][bl], gf = u.C.gsm[jl][1][bl];
                float gg = u.C.gsm[jl][2][bl], go = u.C.gsm[jl][3][bl];
                float si = 1.f/(1.f + __expf(-gi)), sf = 1.f/(1.f + __expf(-gf)), so = 1.f/(1.f + __expf(-go));
                float c2 = sf * P.c0[b*HD + j] + si * tanhf(gg);
                P.c0[b*HD + j] = c2;
                h0n[b*HD + j] = so * tanhf(c2);
            }
        }
        grid_bar(P.bar, ++bk, bid);

        // ---- phase D: LSTM layer 1 (c1 in place), writes H1all[t] ----
        {
            for (int i = tid; i < 8*512; i += 256) {
                int bl = i >> 9, k = i & 511; int b = bL0 + bl;
                u.D.xt[bl][k] = (k < 256) ? h0n[b*HD + k] : h1p[b*HD + k - 256];
            }
            __syncthreads();
            int b_l = tid & 7, gate = (tid >> 3) & 3, j_l = tid >> 5;
            int g = gate*HD + j0 + j_l;
            float accA = P.bih1[g] + P.bhh1[g], accB = 0.f;
            const float4* wi = (const float4*)(P.Wih1 + (size_t)g*HD);
            const float4* xb = (const float4*)u.D.xt[b_l];
            #pragma unroll 4
            for (int k = 0; k < 64; k += 2) {
                float4 w0 = wi[k],   x0 = xb[k];
                float4 w1 = wi[k+1], x1 = xb[k+1];
                accA += w0.x*x0.x + w0.y*x0.y + w0.z*x0.z + w0.w*x0.w;
                accB += w1.x*x1.x + w1.y*x1.y + w1.z*x1.z + w1.w*x1.w;
            }
            const float4* wh = (const float4*)(P.Whh1 + (size_t)g*HD);
            const float4* xh = (const float4*)(u.D.xt[b_l] + 256);
            #pragma unroll 4
            for (int k = 0; k < 64; k += 2) {
                float4 w0 = wh[k],   x0 = xh[k];
                float4 w1 = wh[k+1], x1 = xh[k+1];
                accA += w0.x*x0.x + w0.y*x0.y + w0.z*x0.z + w0.w*x0.w;
                accB += w1.x*x1.x + w1.y*x1.y + w1.z*x1.z + w1.w*x1.w;
            }
            u.D.gsm[j_l][gate][b_l] = accA + accB;
            __syncthreads();
            if (tid < 64) {
                int jl = tid >> 3, bl = tid & 7; int b = bL0 + bl, j = j0 + jl;
                float gi = u.D.gsm[jl][0][bl], gf = u.D.gsm[jl][1][bl];
                float gg = u.D.gsm[jl][2][bl], go = u.D.gsm[jl][3][bl];
                float si = 1.f/(1.f + __expf(-gi)), sf = 1.f/(1.f + __expf(-gf)), so = 1.f/(1.f + __expf(-go));
                float c2 = sf * P.c1[b*HD + j] + si * tanhf(gg);
                P.c1[b*HD + j] = c2;
                h1o[b*HD + j] = so * tanhf(c2);
            }
        }
        grid_bar(P.bar, ++bk, bid);
    }
}

// ---------------- finalization ----------------

__global__ void f1_norm(float* __restrict__ wsout) {
    int t = blockIdx.x, b = blockIdx.y, tid = threadIdx.x;
    float4* row = (float4*)(wsout + ((size_t)b*TT + t)*PP);
    float4 v = row[tid];
    float s = v.x + v.y + v.z + v.w;
    __shared__ float zz[2];
    for (int o = 32; o > 0; o >>= 1) s += __shfl_down(s, o, 64);
    if ((tid & 63) == 0) zz[tid >> 6] = s;
    __syncthreads();
    float r = 1.f / (zz[0] + zz[1]);
    v.x *= r; v.y *= r; v.z *= r; v.w *= r;
    row[tid] = v;
}

__global__ __launch_bounds__(256)
void f2_out(const float* __restrict__ H1all, const float* __restrict__ Wout,
            const float* __restrict__ bout, float* __restrict__ out0) {
    __shared__ float Hs[16][260];
    int vt = blockIdx.x, rt = blockIdx.y, tid = threadIdx.x;
    int r0 = rt * 16;
    for (int i = tid; i < 16*256; i += 256) {
        int rl = i >> 8, c = i & 255;
        Hs[rl][c] = H1all[(size_t)(r0 + rl)*HD + c];
    }
    __syncthreads();
    int r_l = tid & 15, v_l = tid >> 4;
    int r = r0 + r_l; int tt = r >> 6, bb2 = r & 63;
    float* orow = out0 + ((size_t)bb2*TT + tt)*VV;
    const float4* hs = (const float4*)Hs[r_l];
    int vbase = vt*128 + v_l*8;
    for (int i = 0; i < 8; ++i) {
        int v = vbase + i;
        if (v >= VV) break;
        const float4* wr = (const float4*)(Wout + (size_t)v*HD);
        float accA = 0.f, accB = 0.f;
        #pragma unroll 4
        for (int k = 0; k < 64; k += 2) {
            float4 w0 = wr[k],   h0 = hs[k];
            float4 w1 = wr[k+1], h1 = hs[k+1];
            accA += w0.x*h0.x + w0.y*h0.y + w0.z*h0.z + w0.w*h0.w;
            accB += w1.x*h1.x + w1.y*h1.y + w1.z*h1.z + w1.w*h1.w;
        }
        orow[v] = accA + accB + bout[v];
    }
}

// ---------------- host ----------------

extern "C" void kernel_launch(void* const* d_in, const int* in_sizes, int n_in,
                              void* d_out, int out_size, void* d_ws, size_t ws_size,
                              hipStream_t stream) {
    const float* enc    = (const float*)d_in[0];
    const int*   caps   = (const int*)  d_in[1];
    const float* emb    = (const float*)d_in[2];
    const float* Wae    = (const float*)d_in[3];
    const float* bae    = (const float*)d_in[4];
    const float* Wad    = (const float*)d_in[5];
    const float* bad    = (const float*)d_in[6];
    const float* Wfa    = (const float*)d_in[7];
    const float* bfa    = (const float*)d_in[8];
    const float* Winith = (const float*)d_in[9];
    const float* binith = (const float*)d_in[10];
    const float* Winitc = (const float*)d_in[11];
    const float* binitc = (const float*)d_in[12];
    const float* Wih0   = (const float*)d_in[13];
    const float* Whh0   = (const float*)d_in[14];
    const float* bih0   = (const float*)d_in[15];
    const float* bhh0   = (const float*)d_in[16];
    const float* Wih1   = (const float*)d_in[17];
    const float* Whh1   = (const float*)d_in[18];
    const float* bih1   = (const float*)d_in[19];
    const float* bhh1   = (const float*)d_in[20];
    const float* Wout   = (const float*)d_in[21];
    const float* bout   = (const float*)d_in[22];

    // workspace layout (float units); total 16,957,952 floats ≈ 67.8 MB
    float* ws     = (float*)d_ws;
    float* att1T  = ws;                       //  8,388,608
    float* H1all  = ws + 8388608;             //  4,194,304
    unsigned short* encbf = (unsigned short*)(ws + 12582912); // 8,388,608 ushorts
    float* meanb  = ws + 16777216;            //     16,384
    float* h0b    = ws + 16793600;            //     32,768 (double buffer)
    float* c0     = ws + 16826368;            //     16,384 (in-place)
    float* c1     = ws + 16842752;            //     16,384 (in-place)
    float* h1init = ws + 16859136;            //     16,384
    float* att2g  = ws + 16875520;            //     16,384
    float* ctxU   = ws + 16891904;            //     65,536
    float* Zp     = ws + 16957440;            //        256
    unsigned* bar = (unsigned*)(ws + 16957696); // 256 floats = 1 KB barrier region

    float* out0  = (float*)d_out;
    float* wsout = out0 + (size_t)BB*TT*VV;

    hipMemsetAsync((void*)bar, 0, 1024, stream);
    hipLaunchKernelGGL(k_mean,  dim3(BB),      dim3(256), 0, stream, enc, meanb);
    hipLaunchKernelGGL(k_init,  dim3(BB),      dim3(256), 0, stream, meanb, Winith, binith,
                       Winitc, binitc, h0b, c0, h1init, c1);
    hipLaunchKernelGGL(k_att1T, dim3(16, BB),  dim3(512), 0, stream, enc, Wae, bae, att1T);
    hipLaunchKernelGGL(k_encbf, dim3(4096),    dim3(256), 0, stream, enc, encbf);

    KP kp;
    kp.enc = enc; kp.caps = caps; kp.emb = emb;
    kp.Wad = Wad; kp.bad = bad; kp.Wfa = Wfa; kp.bfa = bfa;
    kp.Wih0 = Wih0; kp.Whh0 = Whh0; kp.bih0 = bih0; kp.bhh0 = bhh0;
    kp.Wih1 = Wih1; kp.Whh1 = Whh1; kp.bih1 = bih1; kp.bhh1 = bhh1;
    kp.att1T = att1T; kp.h1init = h1init; kp.encbf = encbf;
    kp.H1all = H1all; kp.h0b = h0b; kp.c0 = c0; kp.c1 = c1;
    kp.att2g = att2g; kp.ctxU = ctxU; kp.Zp = Zp; kp.wsout = wsout;
    kp.bar = bar;

    void* args[] = { &kp };
    hipLaunchCooperativeKernel((const void*)main_loop, dim3(NBLK), dim3(256), args, 0, stream);

    hipLaunchKernelGGL(f1_norm, dim3(TT, BB),   dim3(128), 0, stream, wsout);
    hipLaunchKernelGGL(f2_out,  dim3(16, 1024), dim3(256), 0, stream, H1all, Wout, bout, out0);
}

// Round 4
// 25534.096 us; speedup vs baseline: 1.5778x; 1.4980x over previous
//
#include <hip/hip_runtime.h>
#include <math.h>

#define BB 64
#define TT 256
#define VV 2000
#define EE 256
#define HD 256
#define ENC 256
#define AA 256
#define PP 512   // HI*WI = 16*32

// ---------------- helpers ----------------

__device__ __forceinline__ unsigned short f2bf(float f) {
    unsigned u = __float_as_uint(f);
    return (unsigned short)((u + 0x7fffu + ((u >> 16) & 1u)) >> 16);
}
__device__ __forceinline__ float bflo(unsigned u) { return __uint_as_float(u << 16); }
__device__ __forceinline__ float bfhi(unsigned u) { return __uint_as_float(u & 0xffff0000u); }
__device__ __forceinline__ float dot8(uint4 w, const float* x) {
    return bflo(w.x)*x[0] + bfhi(w.x)*x[1] + bflo(w.y)*x[2] + bfhi(w.y)*x[3]
         + bflo(w.z)*x[4] + bfhi(w.z)*x[5] + bflo(w.w)*x[6] + bfhi(w.w)*x[7];
}

// ---------------- precompute kernels ----------------

__global__ void k_mean(const float* __restrict__ enc, float* __restrict__ meanb) {
    int b = blockIdx.x, c = threadIdx.x;
    const float4* p4 = reinterpret_cast<const float4*>(enc + ((size_t)b*ENC + c)*PP);
    float s = 0.f;
    for (int i = 0; i < PP/4; ++i) { float4 v = p4[i]; s += v.x + v.y + v.z + v.w; }
    meanb[b*ENC + c] = s * (1.0f/PP);
}

__global__ void k_init(const float* __restrict__ meanb,
                       const float* __restrict__ Winith, const float* __restrict__ binith,
                       const float* __restrict__ Winitc, const float* __restrict__ binitc,
                       float* __restrict__ h0, float* __restrict__ c0,
                       float* __restrict__ h1i, float* __restrict__ c1) {
    __shared__ float ms[ENC];
    int b = blockIdx.x, j = threadIdx.x;
    ms[j] = meanb[b*ENC + j];
    __syncthreads();
    float ah = binith[j], ac = binitc[j];
    const float4* wh = (const float4*)(Winith + (size_t)j*ENC);
    const float4* wc = (const float4*)(Winitc + (size_t)j*ENC);
    const float4* m4 = (const float4*)ms;
    for (int k = 0; k < ENC/4; ++k) {
        float4 m = m4[k], a = wh[k], b2 = wc[k];
        ah += a.x*m.x + a.y*m.y + a.z*m.z + a.w*m.w;
        ac += b2.x*m.x + b2.y*m.y + b2.z*m.z + b2.w*m.w;
    }
    float hv = tanhf(ah), cv = tanhf(ac);
    h0[b*HD + j] = hv; c0[b*HD + j] = cv;
    h1i[b*HD + j] = hv; c1[b*HD + j] = cv;
}

// att1P[b][p][a] (bf16) = sum_c enc[b][c][p] * Wae[a][c] + bae[a]
__global__ void k_att1P(const float* __restrict__ enc, const float* __restrict__ Wae,
                        const float* __restrict__ bae, unsigned short* __restrict__ att1P) {
    __shared__ float wsm[16][ENC];
    int a0 = blockIdx.x * 16, b = blockIdx.y, p = threadIdx.x;
    for (int i = threadIdx.x; i < 16*ENC; i += 512) wsm[i >> 8][i & 255] = Wae[(size_t)a0*ENC + i];
    __syncthreads();
    float acc[16];
    #pragma unroll
    for (int i = 0; i < 16; ++i) acc[i] = 0.f;
    const float* eb = enc + (size_t)b*ENC*PP + p;
    for (int c = 0; c < ENC; ++c) {
        float v = eb[(size_t)c*PP];
        #pragma unroll
        for (int i = 0; i < 16; ++i) acc[i] += v * wsm[i][c];
    }
    unsigned short* dst = att1P + ((size_t)b*PP + p)*AA + a0;
    #pragma unroll
    for (int q = 0; q < 4; ++q) {
        ushort4 o = { f2bf(acc[q*4+0] + bae[a0+q*4+0]),
                      f2bf(acc[q*4+1] + bae[a0+q*4+1]),
                      f2bf(acc[q*4+2] + bae[a0+q*4+2]),
                      f2bf(acc[q*4+3] + bae[a0+q*4+3]) };
        *(ushort4*)(dst + q*4) = o;
    }
}

// encP[b][p][c] (bf16) = enc[b][c][p] transposed
__global__ void k_encP(const float* __restrict__ enc, unsigned short* __restrict__ encP) {
    __shared__ float tile[256*33];
    int b = blockIdx.x, p0 = blockIdx.y * 32, tid = threadIdx.x;
    for (int i = tid; i < 256*32; i += 256) {
        int c = i >> 5, pl = i & 31;
        tile[c*33 + pl] = enc[((size_t)b*ENC + c)*PP + p0 + pl];
    }
    __syncthreads();
    for (int j = tid; j < 32*256; j += 256) {
        int p = j >> 8, c = j & 255;
        encP[((size_t)b*PP + p0 + p)*ENC + c] = f2bf(tile[c*33 + p]);
    }
}

// fp32 -> bf16 elementwise (n multiple of 1024)
__global__ void k_cvt(const float* __restrict__ s, unsigned short* __restrict__ d, int n4) {
    int i = blockIdx.x*256 + threadIdx.x;
    if (i < n4) {
        float4 v = ((const float4*)s)[i];
        ushort4 o = { f2bf(v.x), f2bf(v.y), f2bf(v.z), f2bf(v.w) };
        ((ushort4*)d)[i] = o;
    }
}

// ---------------- persistent per-batch-element main loop (no grid sync) ----------------

struct KP2 {
    const int* caps; const float* emb;
    const float* Wfa; const float* bfa; const float* bad;
    const float* bih0; const float* bhh0; const float* bih1; const float* bhh1;
    const unsigned short* Wadb; const unsigned short* Wih0b; const unsigned short* Whh0b;
    const unsigned short* Wih1b; const unsigned short* Whh1b;
    const unsigned short* att1P; const unsigned short* encP;
    const float* h0g; const float* c0g; const float* h1g; const float* c1g;
    float* H1all; float* wsout;
};

__global__ __launch_bounds__(1024, 4) void main64(KP2 P) {
    __shared__ float att2s[AA];          // 1 KB
    __shared__ float xt[512];            // [emb(256) | ctx(256)]
    __shared__ float h0s[HD], h1s[HD];
    __shared__ float es[PP];             // unnormalized softmax
    __shared__ float red[2048];          // partials / gate scratch (aliased)
    __shared__ float bs0[1024], bs1[1024];
    __shared__ float badS[AA], wfaS[AA];
    __shared__ float zinvS, bfaS;
    __shared__ int capS;

    const int b = blockIdx.x, tid = threadIdx.x;

    // one-time preloads
    bs0[tid] = P.bih0[tid] + P.bhh0[tid];
    bs1[tid] = P.bih1[tid] + P.bhh1[tid];
    float c0r = 0.f, c1r = 0.f;
    if (tid < 256) {
        badS[tid] = P.bad[tid]; wfaS[tid] = P.Wfa[tid];
        h0s[tid] = P.h0g[b*HD + tid]; h1s[tid] = P.h1g[b*HD + tid];
        c0r = P.c0g[b*HD + tid];      c1r = P.c1g[b*HD + tid];
    }
    if (tid == 0) bfaS = P.bfa[0];
    __syncthreads();

    const unsigned short* att1Pb = P.att1P + (size_t)b*PP*AA;
    const unsigned short* encPb  = P.encP  + (size_t)b*PP*ENC;

    for (int t = 0; t < TT; ++t) {
        // ---- P1: att2 partials: a = tid>>2, kq = tid&3 (K-chunks of 64) ----
        {
            int a = tid >> 2, kq = tid & 3;
            const uint4* w4 = (const uint4*)(P.Wadb + (size_t)a*AA + kq*64);
            const float* hv = h1s + kq*64;
            float acc = 0.f;
            #pragma unroll
            for (int i = 0; i < 8; ++i) acc += dot8(w4[i], hv + i*8);
            red[kq*256 + a] = acc;
        }
        __syncthreads();
        if (tid < 256) att2s[tid] = red[tid] + red[256+tid] + red[512+tid] + red[768+tid] + badS[tid];
        if (tid == 1023) capS = P.caps[b*TT + t];
        __syncthreads();

        // ---- P2: score: p = tid&511, a-half = tid>>9 ----
        {
            int p = tid & 511, h = tid >> 9;
            const uint4* a4 = (const uint4*)(att1Pb + (size_t)p*AA + h*128);
            float sc = 0.f;
            #pragma unroll 4
            for (int i = 0; i < 16; ++i) {
                uint4 w = a4[i];
                int ab = h*128 + i*8;
                #pragma unroll
                for (int j = 0; j < 4; ++j) {
                    unsigned wj = (&w.x)[j];
                    float x0 = bflo(wj) + att2s[ab + j*2];
                    float x1 = bfhi(wj) + att2s[ab + j*2 + 1];
                    // tanh(x) = 1 - 2/(e^{2x}+1)
                    float r0 = __builtin_amdgcn_rcpf(__expf(2.f*x0) + 1.f);
                    float r1 = __builtin_amdgcn_rcpf(__expf(2.f*x1) + 1.f);
                    sc += wfaS[ab + j*2]     * (1.f - 2.f*r0)
                        + wfaS[ab + j*2 + 1] * (1.f - 2.f*r1);
                }
            }
            red[h*512 + p] = sc;
        }
        __syncthreads();
        if (tid < 512) {
            float e = __expf(red[tid] + red[512 + tid] + bfaS);
            es[tid] = e;
            P.wsout[((size_t)b*TT + t)*PP + tid] = e;   // unnormalized; f1_norm fixes later
        }
        __syncthreads();

        // ---- P3: Z-reduce (wave 0) + ctx partials (all threads) ----
        if (tid < 64) {
            float z = 0.f;
            #pragma unroll
            for (int i = 0; i < 8; ++i) z += es[tid*8 + i];
            for (int o = 32; o > 0; o >>= 1) z += __shfl_down(z, o, 64);
            if (tid == 0) zinvS = 1.f / z;
        }
        {
            int c2 = tid & 127, pq = tid >> 7;   // c-pair, 64 p's each
            float a0 = 0.f, a1 = 0.f;
            #pragma unroll 8
            for (int i = 0; i < 64; ++i) {
                int p = pq*64 + i;
                unsigned w = *(const unsigned*)(encPb + (size_t)p*ENC + c2*2);
                float e = es[p];
                a0 += e * bflo(w); a1 += e * bfhi(w);
            }
            red[pq*256 + c2*2]     = a0;
            red[pq*256 + c2*2 + 1] = a1;
        }
        __syncthreads();
        if (tid < 256) {
            float s = 0.f;
            #pragma unroll
            for (int q = 0; q < 8; ++q) s += red[q*256 + tid];
            xt[256 + tid] = s * zinvS;
        } else if (tid < 512) {
            int j = tid - 256;
            xt[j] = P.emb[(size_t)capS*EE + j];
        }
        __syncthreads();

        // ---- P4: LSTM0 gates: one gate-row per thread ----
        {
            const uint4* wi = (const uint4*)(P.Wih0b + (size_t)tid*512);
            float acc = bs0[tid];
            #pragma unroll 8
            for (int i = 0; i < 64; ++i) acc += dot8(wi[i], &xt[i*8]);
            const uint4* wh = (const uint4*)(P.Whh0b + (size_t)tid*256);
            #pragma unroll 8
            for (int i = 0; i < 32; ++i) acc += dot8(wh[i], &h0s[i*8]);
            red[tid] = acc;
        }
        __syncthreads();
        if (tid < 256) {
            float gi = red[tid], gf = red[HD+tid], gg = red[2*HD+tid], go = red[3*HD+tid];
            float si = 1.f/(1.f + __expf(-gi)), sf = 1.f/(1.f + __expf(-gf)), so = 1.f/(1.f + __expf(-go));
            c0r = sf*c0r + si*tanhf(gg);
            h0s[tid] = so*tanhf(c0r);
        }
        __syncthreads();

        // ---- P5: LSTM1 gates ----
        {
            const uint4* wi = (const uint4*)(P.Wih1b + (size_t)tid*256);
            float acc = bs1[tid];
            #pragma unroll 8
            for (int i = 0; i < 32; ++i) acc += dot8(wi[i], &h0s[i*8]);
            const uint4* wh = (const uint4*)(P.Whh1b + (size_t)tid*256);
            #pragma unroll 8
            for (int i = 0; i < 32; ++i) acc += dot8(wh[i], &h1s[i*8]);
            red[tid] = acc;
        }
        __syncthreads();
        if (tid < 256) {
            float gi = red[tid], gf = red[HD+tid], gg = red[2*HD+tid], go = red[3*HD+tid];
            float si = 1.f/(1.f + __expf(-gi)), sf = 1.f/(1.f + __expf(-gf)), so = 1.f/(1.f + __expf(-go));
            c1r = sf*c1r + si*tanhf(gg);
            float h = so*tanhf(c1r);
            h1s[tid] = h;
            P.H1all[((size_t)t*BB + b)*HD + tid] = h;
        }
        __syncthreads();
    }
}

// ---------------- finalization ----------------

__global__ void f1_norm(float* __restrict__ wsout) {
    int t = blockIdx.x, b = blockIdx.y, tid = threadIdx.x;
    float4* row = (float4*)(wsout + ((size_t)b*TT + t)*PP);
    float4 v = row[tid];
    float s = v.x + v.y + v.z + v.w;
    __shared__ float zz[2];
    for (int o = 32; o > 0; o >>= 1) s += __shfl_down(s, o, 64);
    if ((tid & 63) == 0) zz[tid >> 6] = s;
    __syncthreads();
    float r = 1.f / (zz[0] + zz[1]);
    v.x *= r; v.y *= r; v.z *= r; v.w *= r;
    row[tid] = v;
}

__global__ __launch_bounds__(256)
void f2_out(const float* __restrict__ H1all, const float* __restrict__ Wout,
            const float* __restrict__ bout, float* __restrict__ out0) {
    __shared__ float Hs[16][260];
    int vt = blockIdx.x, rt = blockIdx.y, tid = threadIdx.x;
    int r0 = rt * 16;
    for (int i = tid; i < 16*256; i += 256) {
        int rl = i >> 8, c = i & 255;
        Hs[rl][c] = H1all[(size_t)(r0 + rl)*HD + c];
    }
    __syncthreads();
    int r_l = tid & 15, v_l = tid >> 4;
    int r = r0 + r_l; int tt = r >> 6, bb2 = r & 63;
    float* orow = out0 + ((size_t)bb2*TT + tt)*VV;
    const float4* hs = (const float4*)Hs[r_l];
    int vbase = vt*128 + v_l*8;
    for (int i = 0; i < 8; ++i) {
        int v = vbase + i;
        if (v >= VV) break;
        const float4* wr = (const float4*)(Wout + (size_t)v*HD);
        float accA = 0.f, accB = 0.f;
        #pragma unroll 4
        for (int k = 0; k < 64; k += 2) {
            float4 w0 = wr[k],   h0 = hs[k];
            float4 w1 = wr[k+1], h1 = hs[k+1];
            accA += w0.x*h0.x + w0.y*h0.y + w0.z*h0.z + w0.w*h0.w;
            accB += w1.x*h1.x + w1.y*h1.y + w1.z*h1.z + w1.w*h1.w;
        }
        orow[v] = accA + accB + bout[v];
    }
}

// ---------------- host ----------------

extern "C" void kernel_launch(void* const* d_in, const int* in_sizes, int n_in,
                              void* d_out, int out_size, void* d_ws, size_t ws_size,
                              hipStream_t stream) {
    const float* enc    = (const float*)d_in[0];
    const int*   caps   = (const int*)  d_in[1];
    const float* emb    = (const float*)d_in[2];
    const float* Wae    = (const float*)d_in[3];
    const float* bae    = (const float*)d_in[4];
    const float* Wad    = (const float*)d_in[5];
    const float* bad    = (const float*)d_in[6];
    const float* Wfa    = (const float*)d_in[7];
    const float* bfa    = (const float*)d_in[8];
    const float* Winith = (const float*)d_in[9];
    const float* binith = (const float*)d_in[10];
    const float* Winitc = (const float*)d_in[11];
    const float* binitc = (const float*)d_in[12];
    const float* Wih0   = (const float*)d_in[13];
    const float* Whh0   = (const float*)d_in[14];
    const float* bih0   = (const float*)d_in[15];
    const float* bhh0   = (const float*)d_in[16];
    const float* Wih1   = (const float*)d_in[17];
    const float* Whh1   = (const float*)d_in[18];
    const float* bih1   = (const float*)d_in[19];
    const float* bhh1   = (const float*)d_in[20];
    const float* Wout   = (const float*)d_in[21];
    const float* bout   = (const float*)d_in[22];

    // workspace layout (float units); total 13,352,960 floats ≈ 53.4 MB
    float* ws = (float*)d_ws;
    unsigned short* att1P = (unsigned short*)(ws);             // 8,388,608 ush
    unsigned short* encP  = (unsigned short*)(ws + 4194304);   // 8,388,608 ush
    float* H1all = ws + 8388608;                               // 4,194,304
    unsigned short* Wadb  = (unsigned short*)(ws + 12582912);  //    65,536 ush
    unsigned short* Wih0b = (unsigned short*)(ws + 12615680);  //   524,288 ush
    unsigned short* Whh0b = (unsigned short*)(ws + 12877824);  //   262,144 ush
    unsigned short* Wih1b = (unsigned short*)(ws + 13008896);  //   262,144 ush
    unsigned short* Whh1b = (unsigned short*)(ws + 13139968);  //   262,144 ush
    float* meanb = ws + 13271040;
    float* h0g   = ws + 13287424;
    float* c0g   = ws + 13303808;
    float* h1g   = ws + 13320192;
    float* c1g   = ws + 13336576;

    float* out0  = (float*)d_out;
    float* wsout = out0 + (size_t)BB*TT*VV;

    hipLaunchKernelGGL(k_mean,  dim3(BB),       dim3(256), 0, stream, enc, meanb);
    hipLaunchKernelGGL(k_init,  dim3(BB),       dim3(256), 0, stream, meanb, Winith, binith,
                       Winitc, binitc, h0g, c0g, h1g, c1g);
    hipLaunchKernelGGL(k_att1P, dim3(16, BB),   dim3(512), 0, stream, enc, Wae, bae, att1P);
    hipLaunchKernelGGL(k_encP,  dim3(BB, 16),   dim3(256), 0, stream, enc, encP);
    hipLaunchKernelGGL(k_cvt,   dim3(64),       dim3(256), 0, stream, Wad,  Wadb,  16384);
    hipLaunchKernelGGL(k_cvt,   dim3(512),      dim3(256), 0, stream, Wih0, Wih0b, 131072);
    hipLaunchKernelGGL(k_cvt,   dim3(256),      dim3(256), 0, stream, Whh0, Whh0b, 65536);
    hipLaunchKernelGGL(k_cvt,   dim3(256),      dim3(256), 0, stream, Wih1, Wih1b, 65536);
    hipLaunchKernelGGL(k_cvt,   dim3(256),      dim3(256), 0, stream, Whh1, Whh1b, 65536);

    KP2 kp;
    kp.caps = caps; kp.emb = emb;
    kp.Wfa = Wfa; kp.bfa = bfa; kp.bad = bad;
    kp.bih0 = bih0; kp.bhh0 = bhh0; kp.bih1 = bih1; kp.bhh1 = bhh1;
    kp.Wadb = Wadb; kp.Wih0b = Wih0b; kp.Whh0b = Whh0b; kp.Wih1b = Wih1b; kp.Whh1b = Whh1b;
    kp.att1P = att1P; kp.encP = encP;
    kp.h0g = h0g; kp.c0g = c0g; kp.h1g = h1g; kp.c1g = c1g;
    kp.H1all = H1all; kp.wsout = wsout;

    hipLaunchKernelGGL(main64, dim3(BB), dim3(1024), 0, stream, kp);

    hipLaunchKernelGGL(f1_norm, dim3(TT, BB),   dim3(128), 0, stream, wsout);
    hipLaunchKernelGGL(f2_out,  dim3(16, 1024), dim3(256), 0, stream, H1all, Wout, bout, out0);
}

// Round 5
// 20002.986 us; speedup vs baseline: 2.0141x; 1.2765x over previous
//
#include <hip/hip_runtime.h>
#include <math.h>

#define BB 64
#define TT 256
#define VV 2000
#define EE 256
#define HD 256
#define ENC 256
#define AA 256
#define PP 512   // HI*WI = 16*32

// ---------------- helpers ----------------

__device__ __forceinline__ unsigned short f2bf(float f) {
    unsigned u = __float_as_uint(f);
    return (unsigned short)((u + 0x7fffu + ((u >> 16) & 1u)) >> 16);
}
__device__ __forceinline__ float bflo(unsigned u) { return __uint_as_float(u << 16); }
__device__ __forceinline__ float bfhi(unsigned u) { return __uint_as_float(u & 0xffff0000u); }
__device__ __forceinline__ float dot8(uint4 w, float4 xa, float4 xb) {
    return bflo(w.x)*xa.x + bfhi(w.x)*xa.y + bflo(w.y)*xa.z + bfhi(w.y)*xa.w
         + bflo(w.z)*xb.x + bfhi(w.z)*xb.y + bflo(w.w)*xb.z + bfhi(w.w)*xb.w;
}

// ---------------- precompute kernels ----------------

__global__ void k_mean(const float* __restrict__ enc, float* __restrict__ meanb) {
    int b = blockIdx.x, c = threadIdx.x;
    const float4* p4 = reinterpret_cast<const float4*>(enc + ((size_t)b*ENC + c)*PP);
    float s = 0.f;
    for (int i = 0; i < PP/4; ++i) { float4 v = p4[i]; s += v.x + v.y + v.z + v.w; }
    meanb[b*ENC + c] = s * (1.0f/PP);
}

__global__ void k_init(const float* __restrict__ meanb,
                       const float* __restrict__ Winith, const float* __restrict__ binith,
                       const float* __restrict__ Winitc, const float* __restrict__ binitc,
                       float* __restrict__ h0, float* __restrict__ c0,
                       float* __restrict__ h1i, float* __restrict__ c1) {
    __shared__ float ms[ENC];
    int b = blockIdx.x, j = threadIdx.x;
    ms[j] = meanb[b*ENC + j];
    __syncthreads();
    float ah = binith[j], ac = binitc[j];
    const float4* wh = (const float4*)(Winith + (size_t)j*ENC);
    const float4* wc = (const float4*)(Winitc + (size_t)j*ENC);
    const float4* m4 = (const float4*)ms;
    for (int k = 0; k < ENC/4; ++k) {
        float4 m = m4[k], a = wh[k], b2 = wc[k];
        ah += a.x*m.x + a.y*m.y + a.z*m.z + a.w*m.w;
        ac += b2.x*m.x + b2.y*m.y + b2.z*m.z + b2.w*m.w;
    }
    float hv = tanhf(ah), cv = tanhf(ac);
    h0[b*HD + j] = hv; c0[b*HD + j] = cv;
    h1i[b*HD + j] = hv; c1[b*HD + j] = cv;
}

// att1T8[b][kk][p][j] (bf16) = att1[b][p][a=kk*8+j] = sum_c enc[b][c][p]*Wae[a][c] + bae[a]
__global__ void k_att1T8(const float* __restrict__ enc, const float* __restrict__ Wae,
                         const float* __restrict__ bae, unsigned short* __restrict__ att1T8) {
    __shared__ float wsm[16][ENC];
    int a0 = blockIdx.x * 16, b = blockIdx.y, p = threadIdx.x;
    for (int i = threadIdx.x; i < 16*ENC; i += 512) wsm[i >> 8][i & 255] = Wae[(size_t)a0*ENC + i];
    __syncthreads();
    float acc[16];
    #pragma unroll
    for (int i = 0; i < 16; ++i) acc[i] = 0.f;
    const float* eb = enc + (size_t)b*ENC*PP + p;
    for (int c = 0; c < ENC; ++c) {
        float v = eb[(size_t)c*PP];
        #pragma unroll
        for (int i = 0; i < 16; ++i) acc[i] += v * wsm[i][c];
    }
    #pragma unroll
    for (int q = 0; q < 2; ++q) {
        unsigned short o[8];
        #pragma unroll
        for (int j = 0; j < 8; ++j) o[j] = f2bf(acc[q*8+j] + bae[a0 + q*8 + j]);
        *(uint4*)(att1T8 + (((size_t)b*32 + (a0 >> 3) + q)*PP + p)*8) = *(const uint4*)o;
    }
}

// encP[b][p][c] (bf16) = enc[b][c][p] transposed
__global__ void k_encP(const float* __restrict__ enc, unsigned short* __restrict__ encP) {
    __shared__ float tile[256*33];
    int b = blockIdx.x, p0 = blockIdx.y * 32, tid = threadIdx.x;
    for (int i = tid; i < 256*32; i += 256) {
        int c = i >> 5, pl = i & 31;
        tile[c*33 + pl] = enc[((size_t)b*ENC + c)*PP + p0 + pl];
    }
    __syncthreads();
    for (int j = tid; j < 32*256; j += 256) {
        int p = j >> 8, c = j & 255;
        encP[((size_t)b*PP + p0 + p)*ENC + c] = f2bf(tile[c*33 + p]);
    }
}

// W [N][K] fp32 -> WT8 [K/8][N][8] bf16  (N = 1<<nsh; grid = N*kc/256 blocks)
__global__ void k_cvtT8(const float* __restrict__ src, unsigned short* __restrict__ dst,
                        int nsh, int kc) {
    int i = blockIdx.x*256 + threadIdx.x;
    int N = 1 << nsh;
    int kk = i >> nsh, n = i & (N - 1);
    const float* s = src + (size_t)n*(kc*8) + kk*8;
    unsigned short o[8];
    #pragma unroll
    for (int j = 0; j < 8; ++j) o[j] = f2bf(s[j]);
    *(uint4*)(dst + ((size_t)kk*N + n)*8) = *(const uint4*)o;
}

// ---------------- persistent per-batch-element main loop (no grid sync) ----------------

struct KP2 {
    const int* caps; const float* emb;
    const float* Wfa; const float* bfa; const float* bad;
    const float* bih0; const float* bhh0; const float* bih1; const float* bhh1;
    const unsigned short* WadT8;                       // [32][256][8]
    const unsigned short* Wih0T8;                      // [64][1024][8]
    const unsigned short* Whh0T8;                      // [32][1024][8]
    const unsigned short* Wih1T8;                      // [32][1024][8]
    const unsigned short* Whh1T8;                      // [32][1024][8]
    const unsigned short* att1T8;                      // [b][32][512][8]
    const unsigned short* encP;                        // [b][p][c]
    const float* h0g; const float* c0g; const float* h1g; const float* c1g;
    float* H1all; float* wsout;
};

__global__ __launch_bounds__(1024, 1) void main64(KP2 P) {
    __shared__ float att2s[AA];
    __shared__ float xt[512];            // [emb(256) | ctx(256)]
    __shared__ float h0s[HD], h1s[HD];
    __shared__ float es[PP];
    __shared__ float red[2048];
    __shared__ float bs0[1024], bs1[1024];
    __shared__ float badS[AA], wfaS[AA];
    __shared__ float zinvS, bfaS;
    __shared__ int capS;

    const int b = blockIdx.x, tid = threadIdx.x;

    bs0[tid] = P.bih0[tid] + P.bhh0[tid];
    bs1[tid] = P.bih1[tid] + P.bhh1[tid];
    float c0r = 0.f, c1r = 0.f;
    if (tid < 256) {
        badS[tid] = P.bad[tid]; wfaS[tid] = P.Wfa[tid];
        h0s[tid] = P.h0g[b*HD + tid]; h1s[tid] = P.h1g[b*HD + tid];
        c0r = P.c0g[b*HD + tid];      c1r = P.c1g[b*HD + tid];
    }
    if (tid == 0) bfaS = P.bfa[0];
    __syncthreads();

    const uint4* att1b = (const uint4*)(P.att1T8 + (size_t)b*32*PP*8);
    const unsigned short* encPb = P.encP + (size_t)b*PP*ENC;
    const uint4* wadt = (const uint4*)P.WadT8;
    const uint4* wi0t = (const uint4*)P.Wih0T8;
    const uint4* wh0t = (const uint4*)P.Whh0T8;
    const uint4* wi1t = (const uint4*)P.Wih1T8;
    const uint4* wh1t = (const uint4*)P.Whh1T8;

    for (int t = 0; t < TT; ++t) {
        // ---- P1: att2 partials: a = tid&255, kq = tid>>8 covers kk = kq*8..kq*8+8 ----
        {
            int a = tid & 255, kq = tid >> 8;
            const uint4* w4 = wadt + (size_t)(kq*8)*256 + a;
            float acc = 0.f;
            #pragma unroll
            for (int i = 0; i < 8; ++i) {
                uint4 w = w4[(size_t)i*256];
                const float4* xv = (const float4*)&h1s[(kq*8 + i)*8];
                acc += dot8(w, xv[0], xv[1]);
            }
            red[kq*256 + a] = acc;
        }
        if (tid == 1023) capS = P.caps[b*TT + t];
        __syncthreads();
        if (tid < 256) att2s[tid] = red[tid] + red[256+tid] + red[512+tid] + red[768+tid] + badS[tid];
        __syncthreads();

        // ---- P2: score: p = tid&511, half h = tid>>9 covers kk = h*16..h*16+16 ----
        {
            int p = tid & 511, h = tid >> 9;
            const uint4* a4 = att1b + (size_t)(h*16)*PP + p;
            float sc = 0.f;
            #pragma unroll 4
            for (int i = 0; i < 16; ++i) {
                uint4 w = a4[(size_t)i*PP];
                int ab = (h*16 + i)*8;
                #pragma unroll
                for (int j = 0; j < 4; ++j) {
                    unsigned wj = (&w.x)[j];
                    float x0 = bflo(wj) + att2s[ab + j*2];
                    float x1 = bfhi(wj) + att2s[ab + j*2 + 1];
                    float r0 = __builtin_amdgcn_rcpf(__expf(2.f*x0) + 1.f);   // tanh(x)=1-2/(e^2x+1)
                    float r1 = __builtin_amdgcn_rcpf(__expf(2.f*x1) + 1.f);
                    sc += wfaS[ab + j*2]     * (1.f - 2.f*r0)
                        + wfaS[ab + j*2 + 1] * (1.f - 2.f*r1);
                }
            }
            red[h*512 + p] = sc;
        }
        __syncthreads();
        if (tid < 512) es[tid] = __expf(red[tid] + red[512 + tid] + bfaS);
        __syncthreads();

        // ---- P3: Z (wave 0) + ctx partials (all), then assemble + wsout ----
        if (tid < 64) {
            float z = 0.f;
            #pragma unroll
            for (int i = 0; i < 8; ++i) z += es[tid*8 + i];
            for (int o = 32; o > 0; o >>= 1) z += __shfl_down(z, o, 64);
            if (tid == 0) zinvS = 1.f / z;
        }
        {
            int c2 = tid & 127, pq = tid >> 7;
            float a0 = 0.f, a1 = 0.f;
            #pragma unroll 8
            for (int i = 0; i < 64; ++i) {
                int p = pq*64 + i;
                unsigned w = *(const unsigned*)(encPb + (size_t)p*ENC + c2*2);
                float e = es[p];
                a0 += e * bflo(w); a1 += e * bfhi(w);
            }
            red[pq*256 + c2*2]     = a0;
            red[pq*256 + c2*2 + 1] = a1;
        }
        __syncthreads();
        if (tid < 256) {
            float s = 0.f;
            #pragma unroll
            for (int q = 0; q < 8; ++q) s += red[q*256 + tid];
            xt[256 + tid] = s * zinvS;
        } else if (tid < 512) {
            int j = tid - 256;
            xt[j] = P.emb[(size_t)capS*EE + j];
        } else {
            int p = tid - 512;
            P.wsout[((size_t)b*TT + t)*PP + p] = es[p] * zinvS;
        }
        __syncthreads();

        // ---- P4: LSTM0 gate g = tid ----
        {
            float acc = bs0[tid];
            const uint4* wi = wi0t + tid;
            #pragma unroll 8
            for (int kk = 0; kk < 64; ++kk) {
                uint4 w = wi[(size_t)kk*1024];
                const float4* xv = (const float4*)&xt[kk*8];
                acc += dot8(w, xv[0], xv[1]);
            }
            const uint4* wh = wh0t + tid;
            #pragma unroll 8
            for (int kk = 0; kk < 32; ++kk) {
                uint4 w = wh[(size_t)kk*1024];
                const float4* xv = (const float4*)&h0s[kk*8];
                acc += dot8(w, xv[0], xv[1]);
            }
            red[tid] = acc;
        }
        __syncthreads();
        if (tid < 256) {
            float gi = red[tid], gf = red[HD+tid], gg = red[2*HD+tid], go = red[3*HD+tid];
            float si = 1.f/(1.f + __expf(-gi)), sf = 1.f/(1.f + __expf(-gf)), so = 1.f/(1.f + __expf(-go));
            c0r = sf*c0r + si*tanhf(gg);
            h0s[tid] = so*tanhf(c0r);
        }
        __syncthreads();

        // ---- P5: LSTM1 gate g = tid ----
        {
            float acc = bs1[tid];
            const uint4* wi = wi1t + tid;
            #pragma unroll 8
            for (int kk = 0; kk < 32; ++kk) {
                uint4 w = wi[(size_t)kk*1024];
                const float4* xv = (const float4*)&h0s[kk*8];
                acc += dot8(w, xv[0], xv[1]);
            }
            const uint4* wh = wh1t + tid;
            #pragma unroll 8
            for (int kk = 0; kk < 32; ++kk) {
                uint4 w = wh[(size_t)kk*1024];
                const float4* xv = (const float4*)&h1s[kk*8];
                acc += dot8(w, xv[0], xv[1]);
            }
            red[tid] = acc;
        }
        __syncthreads();
        if (tid < 256) {
            float gi = red[tid], gf = red[HD+tid], gg = red[2*HD+tid], go = red[3*HD+tid];
            float si = 1.f/(1.f + __expf(-gi)), sf = 1.f/(1.f + __expf(-gf)), so = 1.f/(1.f + __expf(-go));
            c1r = sf*c1r + si*tanhf(gg);
            float h = so*tanhf(c1r);
            h1s[tid] = h;
            P.H1all[((size_t)t*BB + b)*HD + tid] = h;
        }
        __syncthreads();
    }
}

// ---------------- finalization ----------------

__global__ __launch_bounds__(256)
void f2_out(const float* __restrict__ H1all, const float* __restrict__ Wout,
            const float* __restrict__ bout, float* __restrict__ out0) {
    __shared__ float Hs[16][260];
    int vt = blockIdx.x, rt = blockIdx.y, tid = threadIdx.x;
    int r0 = rt * 16;
    for (int i = tid; i < 16*256; i += 256) {
        int rl = i >> 8, c = i & 255;
        Hs[rl][c] = H1all[(size_t)(r0 + rl)*HD + c];
    }
    __syncthreads();
    int r_l = tid & 15, v_l = tid >> 4;
    int r = r0 + r_l; int tt = r >> 6, bb2 = r & 63;
    float* orow = out0 + ((size_t)bb2*TT + tt)*VV;
    const float4* hs = (const float4*)Hs[r_l];
    int vbase = vt*128 + v_l*8;
    for (int i = 0; i < 8; ++i) {
        int v = vbase + i;
        if (v >= VV) break;
        const float4* wr = (const float4*)(Wout + (size_t)v*HD);
        float accA = 0.f, accB = 0.f;
        #pragma unroll 4
        for (int k = 0; k < 64; k += 2) {
            float4 w0 = wr[k],   h0 = hs[k];
            float4 w1 = wr[k+1], h1 = hs[k+1];
            accA += w0.x*h0.x + w0.y*h0.y + w0.z*h0.z + w0.w*h0.w;
            accB += w1.x*h1.x + w1.y*h1.y + w1.z*h1.z + w1.w*h1.w;
        }
        orow[v] = accA + accB + bout[v];
    }
}

// ---------------- host ----------------

extern "C" void kernel_launch(void* const* d_in, const int* in_sizes, int n_in,
                              void* d_out, int out_size, void* d_ws, size_t ws_size,
                              hipStream_t stream) {
    const float* enc    = (const float*)d_in[0];
    const int*   caps   = (const int*)  d_in[1];
    const float* emb    = (const float*)d_in[2];
    const float* Wae    = (const float*)d_in[3];
    const float* bae    = (const float*)d_in[4];
    const float* Wad    = (const float*)d_in[5];
    const float* bad    = (const float*)d_in[6];
    const float* Wfa    = (const float*)d_in[7];
    const float* bfa    = (const float*)d_in[8];
    const float* Winith = (const float*)d_in[9];
    const float* binith = (const float*)d_in[10];
    const float* Winitc = (const float*)d_in[11];
    const float* binitc = (const float*)d_in[12];
    const float* Wih0   = (const float*)d_in[13];
    const float* Whh0   = (const float*)d_in[14];
    const float* bih0   = (const float*)d_in[15];
    const float* bhh0   = (const float*)d_in[16];
    const float* Wih1   = (const float*)d_in[17];
    const float* Whh1   = (const float*)d_in[18];
    const float* bih1   = (const float*)d_in[19];
    const float* bhh1   = (const float*)d_in[20];
    const float* Wout   = (const float*)d_in[21];
    const float* bout   = (const float*)d_in[22];

    // workspace layout (float units); total 13,352,960 floats ≈ 53.4 MB
    float* ws = (float*)d_ws;
    unsigned short* att1T8 = (unsigned short*)(ws);             // 8,388,608 ush
    unsigned short* encP   = (unsigned short*)(ws + 4194304);   // 8,388,608 ush
    float* H1all = ws + 8388608;                                // 4,194,304 f
    unsigned short* Wih0T8 = (unsigned short*)(ws + 12582912);  //   524,288 ush
    unsigned short* Whh0T8 = (unsigned short*)(ws + 12845056);  //   262,144 ush
    unsigned short* Wih1T8 = (unsigned short*)(ws + 12976128);  //   262,144 ush
    unsigned short* Whh1T8 = (unsigned short*)(ws + 13107200);  //   262,144 ush
    unsigned short* WadT8  = (unsigned short*)(ws + 13238272);  //    65,536 ush
    float* meanb = ws + 13271040;
    float* h0g   = ws + 13287424;
    float* c0g   = ws + 13303808;
    float* h1g   = ws + 13320192;
    float* c1g   = ws + 13336576;

    float* out0  = (float*)d_out;
    float* wsout = out0 + (size_t)BB*TT*VV;

    hipLaunchKernelGGL(k_mean,   dim3(BB),     dim3(256), 0, stream, enc, meanb);
    hipLaunchKernelGGL(k_init,   dim3(BB),     dim3(256), 0, stream, meanb, Winith, binith,
                       Winitc, binitc, h0g, c0g, h1g, c1g);
    hipLaunchKernelGGL(k_att1T8, dim3(16, BB), dim3(512), 0, stream, enc, Wae, bae, att1T8);
    hipLaunchKernelGGL(k_encP,   dim3(BB, 16), dim3(256), 0, stream, enc, encP);
    hipLaunchKernelGGL(k_cvtT8,  dim3(256),    dim3(256), 0, stream, Wih0, Wih0T8, 10, 64);
    hipLaunchKernelGGL(k_cvtT8,  dim3(128),    dim3(256), 0, stream, Whh0, Whh0T8, 10, 32);
    hipLaunchKernelGGL(k_cvtT8,  dim3(128),    dim3(256), 0, stream, Wih1, Wih1T8, 10, 32);
    hipLaunchKernelGGL(k_cvtT8,  dim3(128),    dim3(256), 0, stream, Whh1, Whh1T8, 10, 32);
    hipLaunchKernelGGL(k_cvtT8,  dim3(32),     dim3(256), 0, stream, Wad,  WadT8,   8, 32);

    KP2 kp;
    kp.caps = caps; kp.emb = emb;
    kp.Wfa = Wfa; kp.bfa = bfa; kp.bad = bad;
    kp.bih0 = bih0; kp.bhh0 = bhh0; kp.bih1 = bih1; kp.bhh1 = bhh1;
    kp.WadT8 = WadT8; kp.Wih0T8 = Wih0T8; kp.Whh0T8 = Whh0T8; kp.Wih1T8 = Wih1T8; kp.Whh1T8 = Whh1T8;
    kp.att1T8 = att1T8; kp.encP = encP;
    kp.h0g = h0g; kp.c0g = c0g; kp.h1g = h1g; kp.c1g = c1g;
    kp.H1all = H1all; kp.wsout = wsout;

    hipLaunchKernelGGL(main64, dim3(BB), dim3(1024), 0, stream, kp);

    hipLaunchKernelGGL(f2_out, dim3(16, 1024), dim3(256), 0, stream, H1all, Wout, bout, out0);
}

// Round 8
// 11908.267 us; speedup vs baseline: 3.3833x; 1.6798x over previous
//
#include <hip/hip_runtime.h>
#include <math.h>

#define BB 64
#define TT 256
#define VV 2000
#define EE 256
#define HD 256
#define ENC 256
#define AA 256
#define PP 512   // HI*WI = 16*32

// ---------------- helpers ----------------

typedef unsigned uvec4 __attribute__((ext_vector_type(4)));

__device__ __forceinline__ unsigned short f2h(float f) {
    _Float16 h = (_Float16)f; return __builtin_bit_cast(unsigned short, h);
}
// a += f16_lo(w) * x   (f32 accumulate)
__device__ __forceinline__ void fmlo(float& a, unsigned w, float x) {
    asm("v_fma_mix_f32 %0, %1, %2, %0 op_sel_hi:[1,0,0]" : "+v"(a) : "v"(w), "v"(x));
}
// a += f16_hi(w) * x
__device__ __forceinline__ void fmhi(float& a, unsigned w, float x) {
    asm("v_fma_mix_f32 %0, %1, %2, %0 op_sel:[1,0,0] op_sel_hi:[1,0,0]" : "+v"(a) : "v"(w), "v"(x));
}
// 8 MACs: w = 8 f16 weights, xa/xb = 8 fp32 x values
__device__ __forceinline__ void dot8m(float& a0, float& a1, uvec4 w, float4 xa, float4 xb) {
    fmlo(a0, w.x, xa.x); fmhi(a1, w.x, xa.y);
    fmlo(a0, w.y, xa.z); fmhi(a1, w.y, xa.w);
    fmlo(a0, w.z, xb.x); fmhi(a1, w.z, xb.y);
    fmlo(a0, w.w, xb.z); fmhi(a1, w.w, xb.w);
}

// ---------------- precompute kernels ----------------

__global__ void k_mean(const float* __restrict__ enc, float* __restrict__ meanb) {
    int b = blockIdx.x, c = threadIdx.x;
    const float4* p4 = reinterpret_cast<const float4*>(enc + ((size_t)b*ENC + c)*PP);
    float s = 0.f;
    for (int i = 0; i < PP/4; ++i) { float4 v = p4[i]; s += v.x + v.y + v.z + v.w; }
    meanb[b*ENC + c] = s * (1.0f/PP);
}

__global__ void k_init(const float* __restrict__ meanb,
                       const float* __restrict__ Winith, const float* __restrict__ binith,
                       const float* __restrict__ Winitc, const float* __restrict__ binitc,
                       float* __restrict__ h0, float* __restrict__ c0,
                       float* __restrict__ h1i, float* __restrict__ c1) {
    __shared__ float ms[ENC];
    int b = blockIdx.x, j = threadIdx.x;
    ms[j] = meanb[b*ENC + j];
    __syncthreads();
    float ah = binith[j], ac = binitc[j];
    const float4* wh = (const float4*)(Winith + (size_t)j*ENC);
    const float4* wc = (const float4*)(Winitc + (size_t)j*ENC);
    const float4* m4 = (const float4*)ms;
    for (int k = 0; k < ENC/4; ++k) {
        float4 m = m4[k], a = wh[k], b2 = wc[k];
        ah += a.x*m.x + a.y*m.y + a.z*m.z + a.w*m.w;
        ac += b2.x*m.x + b2.y*m.y + b2.z*m.z + b2.w*m.w;
    }
    float hv = tanhf(ah), cv = tanhf(ac);
    h0[b*HD + j] = hv; c0[b*HD + j] = cv;
    h1i[b*HD + j] = hv; c1[b*HD + j] = cv;
}

// att1T8[b][kk][p][j] (f16) with kk = a>>3, j = a&7
__global__ void k_att1T8(const float* __restrict__ enc, const float* __restrict__ Wae,
                         const float* __restrict__ bae, unsigned short* __restrict__ att1T8) {
    __shared__ float wsm[16][ENC];
    int a0 = blockIdx.x * 16, b = blockIdx.y, p = threadIdx.x;
    for (int i = threadIdx.x; i < 16*ENC; i += 512) wsm[i >> 8][i & 255] = Wae[(size_t)a0*ENC + i];
    __syncthreads();
    float acc[16];
    #pragma unroll
    for (int i = 0; i < 16; ++i) acc[i] = 0.f;
    const float* eb = enc + (size_t)b*ENC*PP + p;
    for (int c = 0; c < ENC; ++c) {
        float v = eb[(size_t)c*PP];
        #pragma unroll
        for (int i = 0; i < 16; ++i) acc[i] += v * wsm[i][c];
    }
    #pragma unroll
    for (int q = 0; q < 2; ++q) {
        unsigned short o[8];
        #pragma unroll
        for (int j = 0; j < 8; ++j) o[j] = f2h(acc[q*8+j] + bae[a0 + q*8 + j]);
        *(uint4*)(att1T8 + (((size_t)b*32 + (a0 >> 3) + q)*PP + p)*8) = *(const uint4*)o;
    }
}

// encP[b][p][c] (f16) = enc[b][c][p] transposed
__global__ void k_encP(const float* __restrict__ enc, unsigned short* __restrict__ encP) {
    __shared__ float tile[256*33];
    int b = blockIdx.x, p0 = blockIdx.y * 32, tid = threadIdx.x;
    for (int i = tid; i < 256*32; i += 256) {
        int c = i >> 5, pl = i & 31;
        tile[c*33 + pl] = enc[((size_t)b*ENC + c)*PP + p0 + pl];
    }
    __syncthreads();
    for (int j = tid; j < 32*256; j += 256) {
        int p = j >> 8, c = j & 255;
        encP[((size_t)b*PP + p0 + p)*ENC + c] = f2h(tile[c*33 + p]);
    }
}

// W [N][K] fp32 -> WT8 [K/8][N][8] f16  (N = 1<<nsh)
__global__ void k_cvtT8(const float* __restrict__ src, unsigned short* __restrict__ dst,
                        int nsh, int kc) {
    int i = blockIdx.x*256 + threadIdx.x;
    int N = 1 << nsh;
    int kk = i >> nsh, n = i & (N - 1);
    const float* s = src + (size_t)n*(kc*8) + kk*8;
    unsigned short o[8];
    #pragma unroll
    for (int j = 0; j < 8; ++j) o[j] = f2h(s[j]);
    *(uint4*)(dst + ((size_t)kk*N + n)*8) = *(const uint4*)o;
}

// ---------------- persistent per-batch-element main loop (no grid sync) ----------------

struct KP2 {
    const int* caps; const float* emb;
    const float* Wfa; const float* bfa; const float* bad;
    const float* bih0; const float* bhh0; const float* bih1; const float* bhh1;
    const unsigned short* WadT8;                       // [32][256][8]
    const unsigned short* Wih0T8;                      // [64][1024][8]
    const unsigned short* Whh0T8;                      // [32][1024][8]
    const unsigned short* Wih1T8;                      // [32][1024][8]
    const unsigned short* Whh1T8;                      // [32][1024][8]
    const unsigned short* att1T8;                      // [b][32][512][8]
    const unsigned short* encP;                        // [b][p][c]
    const float* h0g; const float* c0g; const float* h1g; const float* c1g;
    float* H1all; float* wsout;
};

__global__ __launch_bounds__(1024, 1) void main64(KP2 P) {
    __shared__ float att2s[AA];
    __shared__ float xt[512];            // [emb(256) | ctx(256)] fp32
    __shared__ float h0s[HD], h1s[HD];   // fp32 state
    __shared__ float es[PP];
    __shared__ float red[2048];
    __shared__ float bs0[1024], bs1[1024];
    __shared__ float badS[AA], wfaS[AA];
    __shared__ float zinvS, bfaS;
    __shared__ int capS;

    const int b = blockIdx.x, tid = threadIdx.x;

    bs0[tid] = P.bih0[tid] + P.bhh0[tid];
    bs1[tid] = P.bih1[tid] + P.bhh1[tid];
    float c0r = 0.f, c1r = 0.f;
    if (tid < 256) {
        badS[tid] = P.bad[tid]; wfaS[tid] = P.Wfa[tid];
        h0s[tid] = P.h0g[b*HD + tid]; h1s[tid] = P.h1g[b*HD + tid];
        c0r = P.c0g[b*HD + tid];      c1r = P.c1g[b*HD + tid];
    }
    if (tid == 0) bfaS = P.bfa[0];
    __syncthreads();

    const uvec4* att1b = (const uvec4*)(P.att1T8 + (size_t)b*32*PP*8);
    const unsigned* encPb = (const unsigned*)(P.encP + (size_t)b*PP*ENC);
    const uvec4* wadt = (const uvec4*)P.WadT8;
    const uvec4* wi0t = (const uvec4*)P.Wih0T8;
    const uvec4* wh0t = (const uvec4*)P.Whh0T8;
    const uvec4* wi1t = (const uvec4*)P.Wih1T8;
    const uvec4* wh1t = (const uvec4*)P.Whh1T8;

    for (int t = 0; t < TT; ++t) {
        // ---- P1: att2 partials: a = tid&255, kq = tid>>8 covers 8 k-octets ----
        {
            int a = tid & 255, kq = tid >> 8;
            const uvec4* w4 = wadt + (size_t)(kq*8)*256 + a;
            const float4* hv = (const float4*)h1s;
            float a0 = 0.f, a1 = 0.f;
            #pragma unroll
            for (int i = 0; i < 8; ++i) {
                uvec4 w = w4[(size_t)i*256];
                dot8m(a0, a1, w, hv[(kq*8 + i)*2], hv[(kq*8 + i)*2 + 1]);
            }
            red[kq*256 + a] = a0 + a1;
        }
        if (tid == 1023) capS = P.caps[b*TT + t];
        __syncthreads();
        if (tid < 256) att2s[tid] = red[tid] + red[256+tid] + red[512+tid] + red[768+tid] + badS[tid];
        __syncthreads();

        // ---- P2: score: p = tid&511, half h = tid>>9 ----
        {
            int p = tid & 511, h = tid >> 9;
            const uvec4* a4 = att1b + (size_t)(h*16)*PP + p;
            float sc = 0.f;
            float one = 1.0f;
            #pragma unroll 4
            for (int i = 0; i < 16; ++i) {
                uvec4 w = __builtin_nontemporal_load(a4 + (size_t)i*PP);
                int ab = (h*16 + i)*8;
                #pragma unroll
                for (int j = 0; j < 4; ++j) {
                    unsigned wj = w[j];
                    float a2l = att2s[ab + j*2], a2h = att2s[ab + j*2 + 1];
                    float x0, x1;
                    asm("v_fma_mix_f32 %0, %1, %2, %3 op_sel_hi:[1,0,0]"
                        : "=v"(x0) : "v"(wj), "v"(one), "v"(a2l));
                    asm("v_fma_mix_f32 %0, %1, %2, %3 op_sel:[1,0,0] op_sel_hi:[1,0,0]"
                        : "=v"(x1) : "v"(wj), "v"(one), "v"(a2h));
                    float r0 = __builtin_amdgcn_rcpf(__expf(2.f*x0) + 1.f);   // tanh(x)=1-2/(e^2x+1)
                    float r1 = __builtin_amdgcn_rcpf(__expf(2.f*x1) + 1.f);
                    sc += wfaS[ab + j*2]     * (1.f - 2.f*r0)
                        + wfaS[ab + j*2 + 1] * (1.f - 2.f*r1);
                }
            }
            red[h*512 + p] = sc;
        }
        __syncthreads();
        if (tid < 512) es[tid] = __expf(red[tid] + red[512 + tid] + bfaS);
        __syncthreads();

        // ---- P3: Z (wave 0) + ctx partials (all) ----
        if (tid < 64) {
            float z = 0.f;
            #pragma unroll
            for (int i = 0; i < 8; ++i) z += es[tid*8 + i];
            for (int o = 32; o > 0; o >>= 1) z += __shfl_down(z, o, 64);
            if (tid == 0) zinvS = 1.f / z;
        }
        {
            int c2 = tid & 127, pq = tid >> 7;
            float a0 = 0.f, a1 = 0.f;
            #pragma unroll 8
            for (int i = 0; i < 64; ++i) {
                int p = pq*64 + i;
                unsigned w = __builtin_nontemporal_load(encPb + (size_t)p*128 + c2);
                float e = es[p];
                fmlo(a0, w, e); fmhi(a1, w, e);
            }
            red[pq*256 + c2*2]     = a0;
            red[pq*256 + c2*2 + 1] = a1;
        }
        __syncthreads();
        // assemble: ctx (tid<256) -> xt[256..512], emb -> xt[0..256], ws out (512..1024)
        if (tid < 256) {
            float s = 0.f;
            #pragma unroll
            for (int q = 0; q < 8; ++q) s += red[q*256 + tid];
            xt[256 + tid] = s * zinvS;
        } else if (tid < 512) {
            int j = tid - 256;
            xt[j] = P.emb[(size_t)capS*EE + j];
        } else {
            int p = tid - 512;
            P.wsout[((size_t)b*TT + t)*PP + p] = es[p] * zinvS;
        }
        __syncthreads();

        // ---- P4: LSTM0 gate g = tid ----
        {
            float a0 = bs0[tid], a1 = 0.f;
            const uvec4* wi = wi0t + tid;
            const float4* xv = (const float4*)xt;
            #pragma unroll 8
            for (int kk = 0; kk < 64; ++kk) {
                uvec4 w = wi[(size_t)kk*1024];
                dot8m(a0, a1, w, xv[kk*2], xv[kk*2 + 1]);
            }
            const uvec4* wh = wh0t + tid;
            const float4* hv = (const float4*)h0s;
            #pragma unroll 8
            for (int kk = 0; kk < 32; ++kk) {
                uvec4 w = wh[(size_t)kk*1024];
                dot8m(a0, a1, w, hv[kk*2], hv[kk*2 + 1]);
            }
            red[tid] = a0 + a1;
        }
        __syncthreads();
        if (tid < 256) {
            float gi = red[tid], gf = red[HD+tid], gg = red[2*HD+tid], go = red[3*HD+tid];
            float si = 1.f/(1.f + __expf(-gi)), sf = 1.f/(1.f + __expf(-gf)), so = 1.f/(1.f + __expf(-go));
            c0r = sf*c0r + si*tanhf(gg);
            h0s[tid] = so*tanhf(c0r);
        }
        __syncthreads();

        // ---- P5: LSTM1 gate g = tid ----
        {
            float a0 = bs1[tid], a1 = 0.f;
            const uvec4* wi = wi1t + tid;
            const float4* hv0 = (const float4*)h0s;
            #pragma unroll 8
            for (int kk = 0; kk < 32; ++kk) {
                uvec4 w = wi[(size_t)kk*1024];
                dot8m(a0, a1, w, hv0[kk*2], hv0[kk*2 + 1]);
            }
            const uvec4* wh = wh1t + tid;
            const float4* hv1 = (const float4*)h1s;
            #pragma unroll 8
            for (int kk = 0; kk < 32; ++kk) {
                uvec4 w = wh[(size_t)kk*1024];
                dot8m(a0, a1, w, hv1[kk*2], hv1[kk*2 + 1]);
            }
            red[tid] = a0 + a1;
        }
        __syncthreads();
        if (tid < 256) {
            float gi = red[tid], gf = red[HD+tid], gg = red[2*HD+tid], go = red[3*HD+tid];
            float si = 1.f/(1.f + __expf(-gi)), sf = 1.f/(1.f + __expf(-gf)), so = 1.f/(1.f + __expf(-go));
            c1r = sf*c1r + si*tanhf(gg);
            float h = so*tanhf(c1r);
            h1s[tid] = h;
            P.H1all[((size_t)t*BB + b)*HD + tid] = h;
        }
        __syncthreads();
    }
}

// ---------------- finalization ----------------

__global__ __launch_bounds__(256)
void f2_out(const float* __restrict__ H1all, const float* __restrict__ Wout,
            const float* __restrict__ bout, float* __restrict__ out0) {
    __shared__ float Hs[16][260];
    int vt = blockIdx.x, rt = blockIdx.y, tid = threadIdx.x;
    int r0 = rt * 16;
    for (int i = tid; i < 16*256; i += 256) {
        int rl = i >> 8, c = i & 255;
        Hs[rl][c] = H1all[(size_t)(r0 + rl)*HD + c];
    }
    __syncthreads();
    int r_l = tid & 15, v_l = tid >> 4;
    int r = r0 + r_l; int tt = r >> 6, bb2 = r & 63;
    float* orow = out0 + ((size_t)bb2*TT + tt)*VV;
    const float4* hs = (const float4*)Hs[r_l];
    int vbase = vt*128 + v_l*8;
    for (int i = 0; i < 8; ++i) {
        int v = vbase + i;
        if (v >= VV) break;
        const float4* wr = (const float4*)(Wout + (size_t)v*HD);
        float accA = 0.f, accB = 0.f;
        #pragma unroll 4
        for (int k = 0; k < 64; k += 2) {
            float4 w0 = wr[k],   h0 = hs[k];
            float4 w1 = wr[k+1], h1 = hs[k+1];
            accA += w0.x*h0.x + w0.y*h0.y + w0.z*h0.z + w0.w*h0.w;
            accB += w1.x*h1.x + w1.y*h1.y + w1.z*h1.z + w1.w*h1.w;
        }
        orow[v] = accA + accB + bout[v];
    }
}

// ---------------- host ----------------

extern "C" void kernel_launch(void* const* d_in, const int* in_sizes, int n_in,
                              void* d_out, int out_size, void* d_ws, size_t ws_size,
                              hipStream_t stream) {
    const float* enc    = (const float*)d_in[0];
    const int*   caps   = (const int*)  d_in[1];
    const float* emb    = (const float*)d_in[2];
    const float* Wae    = (const float*)d_in[3];
    const float* bae    = (const float*)d_in[4];
    const float* Wad    = (const float*)d_in[5];
    const float* bad    = (const float*)d_in[6];
    const float* Wfa    = (const float*)d_in[7];
    const float* bfa    = (const float*)d_in[8];
    const float* Winith = (const float*)d_in[9];
    const float* binith = (const float*)d_in[10];
    const float* Winitc = (const float*)d_in[11];
    const float* binitc = (const float*)d_in[12];
    const float* Wih0   = (const float*)d_in[13];
    const float* Whh0   = (const float*)d_in[14];
    const float* bih0   = (const float*)d_in[15];
    const float* bhh0   = (const float*)d_in[16];
    const float* Wih1   = (const float*)d_in[17];
    const float* Whh1   = (const float*)d_in[18];
    const float* bih1   = (const float*)d_in[19];
    const float* bhh1   = (const float*)d_in[20];
    const float* Wout   = (const float*)d_in[21];
    const float* bout   = (const float*)d_in[22];

    // workspace layout (float units); total ≈ 53.4 MB
    float* ws = (float*)d_ws;
    unsigned short* att1T8 = (unsigned short*)(ws);             // 8,388,608 ush
    unsigned short* encP   = (unsigned short*)(ws + 4194304);   // 8,388,608 ush
    float* H1all = ws + 8388608;                                // 4,194,304 f
    unsigned short* Wih0T8 = (unsigned short*)(ws + 12582912);  //   524,288 ush
    unsigned short* Whh0T8 = (unsigned short*)(ws + 12845056);  //   262,144 ush
    unsigned short* Wih1T8 = (unsigned short*)(ws + 12976128);  //   262,144 ush
    unsigned short* Whh1T8 = (unsigned short*)(ws + 13107200);  //   262,144 ush
    unsigned short* WadT8  = (unsigned short*)(ws + 13238272);  //    65,536 ush
    float* meanb = ws + 13271040;
    float* h0g   = ws + 13287424;
    float* c0g   = ws + 13303808;
    float* h1g   = ws + 13320192;
    float* c1g   = ws + 13336576;

    float* out0  = (float*)d_out;
    float* wsout = out0 + (size_t)BB*TT*VV;

    hipLaunchKernelGGL(k_mean,   dim3(BB),     dim3(256), 0, stream, enc, meanb);
    hipLaunchKernelGGL(k_init,   dim3(BB),     dim3(256), 0, stream, meanb, Winith, binith,
                       Winitc, binitc, h0g, c0g, h1g, c1g);
    hipLaunchKernelGGL(k_att1T8, dim3(16, BB), dim3(512), 0, stream, enc, Wae, bae, att1T8);
    hipLaunchKernelGGL(k_encP,   dim3(BB, 16), dim3(256), 0, stream, enc, encP);
    hipLaunchKernelGGL(k_cvtT8,  dim3(256),    dim3(256), 0, stream, Wih0, Wih0T8, 10, 64);
    hipLaunchKernelGGL(k_cvtT8,  dim3(128),    dim3(256), 0, stream, Whh0, Whh0T8, 10, 32);
    hipLaunchKernelGGL(k_cvtT8,  dim3(128),    dim3(256), 0, stream, Wih1, Wih1T8, 10, 32);
    hipLaunchKernelGGL(k_cvtT8,  dim3(128),    dim3(256), 0, stream, Whh1, Whh1T8, 10, 32);
    hipLaunchKernelGGL(k_cvtT8,  dim3(32),     dim3(256), 0, stream, Wad,  WadT8,   8, 32);

    KP2 kp;
    kp.caps = caps; kp.emb = emb;
    kp.Wfa = Wfa; kp.bfa = bfa; kp.bad = bad;
    kp.bih0 = bih0; kp.bhh0 = bhh0; kp.bih1 = bih1; kp.bhh1 = bhh1;
    kp.WadT8 = WadT8; kp.Wih0T8 = Wih0T8; kp.Whh0T8 = Whh0T8; kp.Wih1T8 = Wih1T8; kp.Whh1T8 = Whh1T8;
    kp.att1T8 = att1T8; kp.encP = encP;
    kp.h0g = h0g; kp.c0g = c0g; kp.h1g = h1g; kp.c1g = c1g;
    kp.H1all = H1all; kp.wsout = wsout;

    hipLaunchKernelGGL(main64, dim3(BB), dim3(1024), 0, stream, kp);

    hipLaunchKernelGGL(f2_out, dim3(16, 1024), dim3(256), 0, stream, H1all, Wout, bout, out0);
}